// Round 1
// baseline (7406.390 us; speedup 1.0000x reference)
//
#include <hip/hip_runtime.h>

// Geometry
static constexpr int ND1 = 160, ND2 = 160, ND3 = 32;
static constexpr int SP  = ND1*ND2*ND3;        // 819200
static constexpr int CO  = 64;
static constexpr int OD1 = 80, OD2 = 80, OD3 = 32;
static constexpr int OSP = OD1*OD2*OD3;        // 204800

// ---------------- mask dtype detection ----------------
// flag bits: 4 -> float32 layout, 1 -> 1-byte (bool) layout, 0 -> int32 layout
__global__ void k_detect(const unsigned char* __restrict__ mb, int* __restrict__ flag)
{
    __shared__ int lf;
    if (threadIdx.x == 0) lf = 0;
    __syncthreads();
    int f = 0;
    for (int i = blockIdx.x*256 + threadIdx.x; i < SP; i += gridDim.x*256) {
        unsigned char b = mb[i];
        if (b > 1) f |= 4;
        if (b != 0 && (i & 3)) f |= 1;
    }
    if (f) atomicOr(&lf, f);
    __syncthreads();
    if (threadIdx.x == 0 && lf) atomicOr(flag, lf);
}

__global__ void k_mask(const void* __restrict__ mraw, const int* __restrict__ flag,
                       float* __restrict__ m, float* __restrict__ nact)
{
    int i = blockIdx.x*256 + threadIdx.x;
    int f = *flag;
    float v;
    if (f & 4)      v = (reinterpret_cast<const float*>(mraw)[i] != 0.f) ? 1.f : 0.f;
    else if (f & 1) v = (reinterpret_cast<const unsigned char*>(mraw)[i] != 0) ? 1.f : 0.f;
    else            v = (reinterpret_cast<const int*>(mraw)[i] != 0) ? 1.f : 0.f;
    m[i] = v;
    float s = v;
    #pragma unroll
    for (int off = 32; off > 0; off >>= 1) s += __shfl_xor(s, off);
    __shared__ float wsum[4];
    if ((threadIdx.x & 63) == 0) wsum[threadIdx.x >> 6] = s;
    __syncthreads();
    if (threadIdx.x == 0) atomicAdd(nact, wsum[0]+wsum[1]+wsum[2]+wsum[3]);
}

__global__ void k_outmask(const float* __restrict__ m, float* __restrict__ om)
{
    int i = blockIdx.x*256 + threadIdx.x;   // < OSP
    int o3 = i & 31; int t = i >> 5; int o2 = t % OD2; int o1 = t / OD2;
    float s = 0.f;
    for (int kd = 0; kd < 3; kd++) { int d1 = 2*o1 - 1 + kd; if ((unsigned)d1 >= ND1) continue;
      for (int kh = 0; kh < 3; kh++) { int d2 = 2*o2 - 1 + kh; if ((unsigned)d2 >= ND2) continue;
        for (int kw = 0; kw < 3; kw++) { int d3 = o3 - 1 + kw; if ((unsigned)d3 >= ND3) continue;
          s += m[(d1*ND2 + d2)*ND3 + d3];
        } } }
    om[i] = (s > 0.f) ? 1.f : 0.f;
}

// ---------------- BN finalize: stats -> per-channel affine ----------------
__global__ void k_finalize(const float* __restrict__ s1, const float* __restrict__ s2,
                           const float* __restrict__ nact,
                           const float* __restrict__ g, const float* __restrict__ b,
                           float* __restrict__ scsh)
{
    int c = threadIdx.x;      // 64 threads
    float n = *nact;
    float mean = s1[c] / n;
    float var  = s2[c] / n - mean*mean;
    float inv  = rsqrtf(var + 1e-5f);
    float sc   = inv * g[c];
    scsh[c]      = sc;
    scsh[64 + c] = b[c] - mean*sc;
}

// ---------------- final combine: res_B = (affA2(hA2)+affB2(hB2))*m ----------------
__global__ void k_final(const float* __restrict__ hA2, float* __restrict__ outB,
                        const float* __restrict__ sA, const float* __restrict__ sB,
                        const float* __restrict__ m)
{
    const int total = CO*SP/4;
    for (int i = blockIdx.x*blockDim.x + threadIdx.x; i < total; i += gridDim.x*blockDim.x) {
        int c   = i / (SP/4);
        int sp4 = i - c*(SP/4);
        float4 a  = reinterpret_cast<const float4*>(hA2)[i];
        float4 bb = reinterpret_cast<const float4*>(outB)[i];
        float4 mm = reinterpret_cast<const float4*>(m)[sp4];
        float sa = sA[c], ta = sA[64+c], sb = sB[c], tb = sB[64+c];
        float4 o;
        o.x = (a.x*sa + ta + bb.x*sb + tb) * mm.x;
        o.y = (a.y*sa + ta + bb.y*sb + tb) * mm.y;
        o.z = (a.z*sa + ta + bb.z*sb + tb) * mm.z;
        o.w = (a.w*sa + ta + bb.w*sb + tb) * mm.w;
        reinterpret_cast<float4*>(outB)[i] = o;
    }
}

// ---------------- conv kernels ----------------
// KIND 0: taps (3,1,3)  (d1 +/-1, d3 +/-1)
// KIND 1: taps (1,3,3)  (d2 +/-1, d3 +/-1)
// KIND 2: pool 3x3x3, stride (2,2,1), pad 1
// Block: 8 out d2-rows x 32 d3 x 64 cout. 256 threads; lane -> 16 cout x 4 d3.
template<int KIND, int CIN>
__launch_bounds__(256, 2)
__global__ void conv_kernel(const float* __restrict__ in,
                            const float* __restrict__ Wg,
                            const float* __restrict__ scsh,    // null or [scale64][shift64]
                            const float* __restrict__ mstage,  // null or mask (input voxel)
                            const float* __restrict__ mout,    // mask (conv9) or out_mask (pool)
                            float* __restrict__ out,
                            float* __restrict__ s1p, float* __restrict__ s2p)
{
    constexpr int NLINES = (KIND == 2) ? 9 : 3;
    constexpr int NTAPS  = NLINES*3;
    constexpr int NP     = (KIND == 1) ? 1 : 3;
    constexpr int NR     = (KIND == 2) ? 17 : ((KIND == 1) ? 10 : 8);
    constexpr int CHUNK  = (KIND == 2) ? 4 : 8;
    constexpr int ROWST  = 35;                   // padded (34 used)
    constexpr int CISZ   = NP*NR*ROWST;

    __shared__ __align__(16) float tileS[CHUNK*CISZ];
    __shared__ __align__(16) float wS[CHUNK*NTAPS*64];

    const int tid  = threadIdx.x;
    const int wave = tid >> 6, lane = tid & 63;
    const int r    = lane >> 3;            // out-row within tile (0..7)
    const int d3b  = (lane & 7)*4;         // d3 base (0,4,..,28)
    const int co0  = wave*16;
    const int r0   = blockIdx.x*8;         // d2 (or o2) tile base
    const int z1   = blockIdx.y;           // d1 (or o1)

    float acc[16][4];
    #pragma unroll
    for (int q = 0; q < 16; q++)
        #pragma unroll
        for (int j = 0; j < 4; j++) acc[q][j] = 0.f;

    for (int ci0 = 0; ci0 < CIN; ci0 += CHUNK) {
        __syncthreads();
        // ---- stage input tile (with optional affine + mask transform) ----
        for (int idx = tid; idx < CHUNK*NP*NR*34; idx += 256) {
            int col = idx % 34;
            int t   = idx / 34;
            int row = t % NR;  t /= NR;
            int p   = t % NP;
            int cil = t / NP;
            int ci  = ci0 + cil;
            int sd1, sd2, sd3 = col - 1;
            if (KIND == 0)      { sd1 = z1 - 1 + p;   sd2 = r0 + row;       }
            else if (KIND == 1) { sd1 = z1;           sd2 = r0 - 1 + row;   }
            else                { sd1 = 2*z1 - 1 + p; sd2 = 2*r0 - 1 + row; }
            float v = 0.f;
            if ((unsigned)sd1 < (unsigned)ND1 && (unsigned)sd2 < (unsigned)ND2 &&
                (unsigned)sd3 < (unsigned)ND3) {
                int sp = (sd1*ND2 + sd2)*ND3 + sd3;
                v = in[(size_t)ci*SP + sp];
                if (scsh)   v = v*scsh[ci] + scsh[64 + ci];
                if (mstage) v *= mstage[sp];
            }
            tileS[(cil*NP + p)*NR*ROWST + row*ROWST + col] = v;
        }
        // ---- stage weights: wS[cil][tap][co] ----
        for (int idx = tid; idx < CHUNK*NTAPS*64; idx += 256) {
            int co  = idx & 63;
            int t   = idx >> 6;
            int tap = t % NTAPS;
            int cil = t / NTAPS;
            wS[idx] = Wg[((size_t)co*CIN + ci0 + cil)*NTAPS + tap];
        }
        __syncthreads();
        // ---- compute ----
        for (int cil = 0; cil < CHUNK; cil++) {
            const float* tci = &tileS[cil*CISZ];
            const float* wci = &wS[cil*NTAPS*64];
            #pragma unroll
            for (int line = 0; line < NLINES; line++) {
                const int p    = (KIND == 0) ? line : ((KIND == 2) ? line/3 : 0);
                const int rowi = (KIND == 0) ? r : ((KIND == 1) ? r + line : 2*r + line%3);
                const float* rowp = &tci[(p*NR + rowi)*ROWST + d3b];
                float win[6];
                #pragma unroll
                for (int j = 0; j < 6; j++) win[j] = rowp[j];
                #pragma unroll
                for (int kw = 0; kw < 3; kw++) {
                    const float4* wp = reinterpret_cast<const float4*>(&wci[(line*3 + kw)*64 + co0]);
                    float wv[16];
                    #pragma unroll
                    for (int u = 0; u < 4; u++) {
                        float4 t4 = wp[u];
                        wv[4*u] = t4.x; wv[4*u+1] = t4.y; wv[4*u+2] = t4.z; wv[4*u+3] = t4.w;
                    }
                    #pragma unroll
                    for (int q = 0; q < 16; q++)
                        #pragma unroll
                        for (int j = 0; j < 4; j++)
                            acc[q][j] = fmaf(wv[q], win[j + kw], acc[q][j]);
                }
            }
        }
    }

    // ---- epilogue: mask, lrelu, store, fused stats ----
    const int orow = r0 + r;
    const int osp  = (KIND == 2) ? ((z1*OD2 + orow)*OD3 + d3b)
                                 : ((z1*ND2 + orow)*ND3 + d3b);
    const int ospan = (KIND == 2) ? OSP : SP;
    float mv[4];
    #pragma unroll
    for (int j = 0; j < 4; j++) mv[j] = mout[osp + j];

    float s1l[16], s2l[16];
    #pragma unroll
    for (int q = 0; q < 16; q++) {
        float h[4]; float t1 = 0.f, t2 = 0.f;
        #pragma unroll
        for (int j = 0; j < 4; j++) {
            float v = acc[q][j]*mv[j];
            if (KIND != 2) v = (v >= 0.f) ? v : 0.01f*v;
            h[j] = v; t1 += v; t2 += v*v;
        }
        float4 hv = make_float4(h[0], h[1], h[2], h[3]);
        *reinterpret_cast<float4*>(&out[(size_t)(co0 + q)*ospan + osp]) = hv;
        s1l[q] = t1; s2l[q] = t2;
    }
    if (s1p) {
        #pragma unroll
        for (int q = 0; q < 16; q++) {
            float a = s1l[q], b = s2l[q];
            for (int off = 32; off > 0; off >>= 1) {
                a += __shfl_xor(a, off);
                b += __shfl_xor(b, off);
            }
            if (lane == 0) {
                atomicAdd(&s1p[co0 + q], a);
                atomicAdd(&s2p[co0 + q], b);
            }
        }
    }
}

// ---------------- launch ----------------
extern "C" void kernel_launch(void* const* d_in, const int* in_sizes, int n_in,
                              void* d_out, int out_size, void* d_ws, size_t ws_size,
                              hipStream_t stream)
{
    const float* x      = (const float*)d_in[0];
    const void*  mraw   = d_in[1];
    const float* W_A1   = (const float*)d_in[2];
    const float* W_A2   = (const float*)d_in[3];
    const float* W_B1   = (const float*)d_in[4];
    const float* W_B2   = (const float*)d_in[5];
    const float* W_pool = (const float*)d_in[6];
    const float* g_A1 = (const float*)d_in[7],  *b_A1 = (const float*)d_in[8];
    const float* g_A2 = (const float*)d_in[9],  *b_A2 = (const float*)d_in[10];
    const float* g_B1 = (const float*)d_in[11], *b_B1 = (const float*)d_in[12];
    const float* g_B2 = (const float*)d_in[13], *b_B2 = (const float*)d_in[14];

    float* ws    = (float*)d_ws;
    float* m     = ws;                               // SP
    float* buf1  = m + SP;                           // CO*SP  (h_A1 / h_B1)
    float* buf2  = buf1 + (size_t)CO*SP;             // CO*SP  (h_A2)
    float* omask = buf2 + (size_t)CO*SP;             // OSP
    float* stats = omask + OSP;                      // 4 stages * 2 * 64
    float* scsh  = stats + 4*128;                    // 4 stages * 2 * 64
    float* nact  = scsh + 4*128;                     // 1
    int*   flag  = (int*)(nact + 1);                 // 1
    // total ~424 MB of d_ws

    float* down = (float*)d_out;                     // CO*OSP
    float* outB = down + (size_t)CO*OSP;             // CO*SP

    hipMemsetAsync(stats, 0, (4*128 + 4*128 + 2)*sizeof(float), stream);
    k_detect<<<256, 256, 0, stream>>>((const unsigned char*)mraw, flag);
    k_mask<<<SP/256, 256, 0, stream>>>(mraw, flag, m, nact);
    k_outmask<<<OSP/256, 256, 0, stream>>>(m, omask);

    dim3 g9(20, 160), gp(10, 80);
    // A1: conv(3,1,3) on xs, Cin=32
    conv_kernel<0,32><<<g9, 256, 0, stream>>>(x, W_A1, nullptr, m, m, buf1,
                                              stats + 0, stats + 64);
    k_finalize<<<1, 64, 0, stream>>>(stats + 0, stats + 64, nact, g_A1, b_A1, scsh + 0);
    // A2: conv(1,3,3) on res_A, Cin=64 (BN_A1 fused into staging)
    conv_kernel<1,64><<<g9, 256, 0, stream>>>(buf1, W_A2, scsh + 0, m, m, buf2,
                                              stats + 128, stats + 192);
    k_finalize<<<1, 64, 0, stream>>>(stats + 128, stats + 192, nact, g_A2, b_A2, scsh + 128);
    // B1: conv(1,3,3) on xs, Cin=32
    conv_kernel<1,32><<<g9, 256, 0, stream>>>(x, W_B1, nullptr, m, m, buf1,
                                              stats + 256, stats + 320);
    k_finalize<<<1, 64, 0, stream>>>(stats + 256, stats + 320, nact, g_B1, b_B1, scsh + 256);
    // B2: conv(3,1,3) on res_B1, Cin=64 (BN_B1 fused into staging); h_B2 -> d_out resB region
    conv_kernel<0,64><<<g9, 256, 0, stream>>>(buf1, W_B2, scsh + 256, m, m, outB,
                                              stats + 384, stats + 448);
    k_finalize<<<1, 64, 0, stream>>>(stats + 384, stats + 448, nact, g_B2, b_B2, scsh + 384);
    // res_B = (affA2(hA2) + affB2(hB2)) * m, in place in d_out
    k_final<<<2048, 256, 0, stream>>>(buf2, outB, scsh + 128, scsh + 384, m);
    // pooled conv 3x3x3 stride (2,2,1) * out_mask
    conv_kernel<2,64><<<gp, 256, 0, stream>>>(outB, W_pool, nullptr, nullptr, omask, down,
                                              nullptr, nullptr);
}

// Round 2
// 1188.956 us; speedup vs baseline: 6.2293x; 6.2293x over previous
//
#include <hip/hip_runtime.h>

static constexpr int ND1=160, ND2=160, ND3=32;
static constexpr int SP  = ND1*ND2*ND3;        // 819200
static constexpr int CO  = 64;
static constexpr int OD1=80, OD2=80, OD3=32;
static constexpr int OSP = OD1*OD2*OD3;        // 204800

typedef __attribute__((ext_vector_type(8))) short  short8;
typedef __attribute__((ext_vector_type(4))) float  f32x4;

__device__ __forceinline__ float b2f(unsigned u){ return __uint_as_float(u<<16); }
__device__ __forceinline__ unsigned short f2b(float f){
    unsigned u = __float_as_uint(f);
    u += 0x7fffu + ((u>>16)&1u);
    return (unsigned short)(u>>16);
}

// ---------------- mask dtype detection ----------------
__global__ void k_detect(const unsigned char* __restrict__ mb, int* __restrict__ flag)
{
    __shared__ int lf;
    if (threadIdx.x == 0) lf = 0;
    __syncthreads();
    int f = 0;
    for (int i = blockIdx.x*256 + threadIdx.x; i < SP; i += gridDim.x*256) {
        unsigned char b = mb[i];
        if (b > 1) f |= 4;
        if (b != 0 && (i & 3)) f |= 1;
    }
    if (f) atomicOr(&lf, f);
    __syncthreads();
    if (threadIdx.x == 0 && lf) atomicOr(flag, lf);
}

__global__ void k_mask(const void* __restrict__ mraw, const int* __restrict__ flag,
                       float* __restrict__ m, float* __restrict__ nact)
{
    int i = blockIdx.x*256 + threadIdx.x;
    int f = *flag;
    float v;
    if (f & 4)      v = (reinterpret_cast<const float*>(mraw)[i] != 0.f) ? 1.f : 0.f;
    else if (f & 1) v = (reinterpret_cast<const unsigned char*>(mraw)[i] != 0) ? 1.f : 0.f;
    else            v = (reinterpret_cast<const int*>(mraw)[i] != 0) ? 1.f : 0.f;
    m[i] = v;
    float s = v;
    #pragma unroll
    for (int off = 32; off > 0; off >>= 1) s += __shfl_xor(s, off);
    __shared__ float wsum[4];
    if ((threadIdx.x & 63) == 0) wsum[threadIdx.x >> 6] = s;
    __syncthreads();
    if (threadIdx.x == 0) atomicAdd(nact, wsum[0]+wsum[1]+wsum[2]+wsum[3]);
}

__global__ void k_outmask(const float* __restrict__ m, float* __restrict__ om)
{
    int i = blockIdx.x*256 + threadIdx.x;   // < OSP
    int o3 = i & 31; int t = i >> 5; int o2 = t % OD2; int o1 = t / OD2;
    float s = 0.f;
    for (int kd = 0; kd < 3; kd++) { int d1 = 2*o1 - 1 + kd; if ((unsigned)d1 >= ND1) continue;
      for (int kh = 0; kh < 3; kh++) { int d2 = 2*o2 - 1 + kh; if ((unsigned)d2 >= ND2) continue;
        for (int kw = 0; kw < 3; kw++) { int d3 = o3 - 1 + kw; if ((unsigned)d3 >= ND3) continue;
          s += m[(d1*ND2 + d2)*ND3 + d3];
        } } }
    om[i] = (s > 0.f) ? 1.f : 0.f;
}

// ---------------- BN finalize ----------------
__global__ void k_finalize(const float* __restrict__ s1, const float* __restrict__ s2,
                           const float* __restrict__ nact,
                           const float* __restrict__ g, const float* __restrict__ b,
                           float* __restrict__ scsh)
{
    int c = threadIdx.x;      // 64 threads
    float n = *nact;
    float mean = s1[c] / n;
    float var  = s2[c] / n - mean*mean;
    float inv  = rsqrtf(var + 1e-5f);
    float sc   = inv * g[c];
    scsh[c]      = sc;
    scsh[64 + c] = b[c] - mean*sc;
}

// ---------------- weight pre-pack: W[co][ci][tap] f32 -> Wt[kc][co][32] bf16 ----------------
__global__ void k_wprep(const float* __restrict__ W, unsigned short* __restrict__ Wt,
                        int CIN, int NT)
{
    int i = blockIdx.x*256 + threadIdx.x;
    int K = CIN*NT;
    if (i >= 64*K) return;
    int ksub = i & 31;
    int t = i >> 5;
    int co = t & 63;
    int kc = t >> 6;
    int nch = CIN >> 5;
    int tap = kc / nch;
    int ci  = (kc - tap*nch)*32 + ksub;
    Wt[i] = f2b(W[((size_t)co*CIN + ci)*NT + tap]);
}

// ---------------- x f32 [ci][sp] -> masked bf16 [sp][32] (tiled transpose) ----------------
__global__ void k_prep_x(const float* __restrict__ x, const float* __restrict__ m,
                         unsigned short* __restrict__ xt)
{
    __shared__ float t[64][33];
    int sp0 = blockIdx.x*64;
    int tid = threadIdx.x;
    int c = tid>>6, s = tid&63;
    float mm = m[sp0+s];
    #pragma unroll
    for (int r=0;r<8;r++){
        int ci = c + r*4;
        t[s][ci] = x[(size_t)ci*SP + sp0 + s]*mm;
    }
    __syncthreads();
    int sp = tid>>2, c0 = (tid&3)*8;
    unsigned short o[8];
    #pragma unroll
    for (int i=0;i<8;i++) o[i] = f2b(t[sp][c0+i]);
    uint4 pk;
    pk.x = o[0] | ((unsigned)o[1]<<16);
    pk.y = o[2] | ((unsigned)o[3]<<16);
    pk.z = o[4] | ((unsigned)o[5]<<16);
    pk.w = o[6] | ((unsigned)o[7]<<16);
    *reinterpret_cast<uint4*>(xt + (size_t)(sp0+sp)*32 + c0) = pk;
}

// ---------------- in-place BN affine + mask on bf16 [sp][64] ----------------
__global__ void k_affine(unsigned short* __restrict__ h, const float* __restrict__ scsh,
                         const float* __restrict__ m)
{
    __shared__ float ss[128];
    int tid = threadIdx.x;
    if (tid < 128) ss[tid] = scsh[tid];
    __syncthreads();
    int i = blockIdx.x*256 + tid;          // < SP*8
    int sp = i >> 3;
    int c0 = (i & 7) * 8;
    float mm = m[sp];
    uint4 pk = *reinterpret_cast<uint4*>(h + (size_t)sp*64 + c0);
    unsigned us[8] = {pk.x&0xffffu, pk.x>>16, pk.y&0xffffu, pk.y>>16,
                      pk.z&0xffffu, pk.z>>16, pk.w&0xffffu, pk.w>>16};
    unsigned short o[8];
    #pragma unroll
    for (int q=0;q<8;q++){
        float v = (b2f(us[q])*ss[c0+q] + ss[64+c0+q])*mm;
        o[q] = f2b(v);
    }
    uint4 po;
    po.x = o[0] | ((unsigned)o[1]<<16);
    po.y = o[2] | ((unsigned)o[3]<<16);
    po.z = o[4] | ((unsigned)o[5]<<16);
    po.w = o[6] | ((unsigned)o[7]<<16);
    *reinterpret_cast<uint4*>(h + (size_t)sp*64 + c0) = po;
}

// ---------------- res_B = (affA(hA)+affB(hB))*m -> bf16 [sp][64] + f32 [ci][sp] ----------------
__global__ void k_resB(const unsigned short* __restrict__ hA, const unsigned short* __restrict__ hB,
                       const float* __restrict__ sA, const float* __restrict__ sB,
                       const float* __restrict__ m,
                       unsigned short* __restrict__ rbt, float* __restrict__ resf)
{
    __shared__ float t[64][65];
    __shared__ float ss[256];
    int tid = threadIdx.x;
    if (tid < 128){ ss[tid] = sA[tid]; ss[128+tid] = sB[tid]; }
    __syncthreads();
    int sp0 = blockIdx.x*64;
    int sp = tid>>2, c0 = (tid&3)*16;
    float mm = m[sp0+sp];
    const size_t base = (size_t)(sp0+sp)*64 + c0;
    uint4 a0 = *reinterpret_cast<const uint4*>(hA + base);
    uint4 a1 = *reinterpret_cast<const uint4*>(hA + base + 8);
    uint4 b0 = *reinterpret_cast<const uint4*>(hB + base);
    uint4 b1 = *reinterpret_cast<const uint4*>(hB + base + 8);
    unsigned ua[16] = {a0.x&0xffffu,a0.x>>16,a0.y&0xffffu,a0.y>>16,a0.z&0xffffu,a0.z>>16,a0.w&0xffffu,a0.w>>16,
                       a1.x&0xffffu,a1.x>>16,a1.y&0xffffu,a1.y>>16,a1.z&0xffffu,a1.z>>16,a1.w&0xffffu,a1.w>>16};
    unsigned ub[16] = {b0.x&0xffffu,b0.x>>16,b0.y&0xffffu,b0.y>>16,b0.z&0xffffu,b0.z>>16,b0.w&0xffffu,b0.w>>16,
                       b1.x&0xffffu,b1.x>>16,b1.y&0xffffu,b1.y>>16,b1.z&0xffffu,b1.z>>16,b1.w&0xffffu,b1.w>>16};
    unsigned short o[16];
    #pragma unroll
    for (int q=0;q<16;q++){
        int ci = c0+q;
        float v = (b2f(ua[q])*ss[ci] + ss[64+ci] + b2f(ub[q])*ss[128+ci] + ss[192+ci])*mm;
        t[sp][ci] = v;
        o[q] = f2b(v);
    }
    uint4 p0, p1;
    p0.x = o[0]|((unsigned)o[1]<<16);  p0.y = o[2]|((unsigned)o[3]<<16);
    p0.z = o[4]|((unsigned)o[5]<<16);  p0.w = o[6]|((unsigned)o[7]<<16);
    p1.x = o[8]|((unsigned)o[9]<<16);  p1.y = o[10]|((unsigned)o[11]<<16);
    p1.z = o[12]|((unsigned)o[13]<<16); p1.w = o[14]|((unsigned)o[15]<<16);
    *reinterpret_cast<uint4*>(rbt + base)     = p0;
    *reinterpret_cast<uint4*>(rbt + base + 8) = p1;
    __syncthreads();
    int ci = tid>>2, s0 = (tid&3)*16;
    #pragma unroll
    for (int kq=0;kq<4;kq++){
        float4 ov;
        ov.x = t[s0+4*kq+0][ci]; ov.y = t[s0+4*kq+1][ci];
        ov.z = t[s0+4*kq+2][ci]; ov.w = t[s0+4*kq+3][ci];
        *reinterpret_cast<float4*>(resf + (size_t)ci*SP + sp0 + s0 + 4*kq) = ov;
    }
}

// ---------------- MFMA conv ----------------
// KIND 0: taps (3,1,3); KIND 1: taps (1,3,3); KIND 2: pool 3x3x3 stride (2,2,1)
// Block: 256 thr = 4 waves. Output tile: 64 cout x (8 d2-rows x 32 d3). Wave w: rows w*2..w*2+1.
// A = weights (M=co), B = input bf16 channel-last (N=sp), fp32 acc.
template<int KIND, int CIN>
__launch_bounds__(256, 3)
__global__ void mconv(const unsigned short* __restrict__ in,   // bf16 [vox][CIN]
                      const unsigned short* __restrict__ Wt,   // bf16 [kc][64][32]
                      const float* __restrict__ mout,          // mask at output voxel
                      unsigned short* __restrict__ outb,       // bf16 [vox][64] (KIND 0/1)
                      float* __restrict__ outf,                // f32 [co][OSP] (KIND 2)
                      float* __restrict__ statsg)              // [s1 64][s2 64]
{
    constexpr int KD  = (KIND==1) ? 1 : 3;
    constexpr int KH  = (KIND==0) ? 1 : 3;
    constexpr int NCH = CIN/32;
    constexpr int D1o = (KIND==2) ? OD1 : ND1;
    constexpr int NT2 = (KIND==2) ? (OD2/8) : (ND2/8);
    constexpr int ZPX = D1o/8;
    __shared__ float sst[128];

    const int tid = threadIdx.x;
    const int w = tid>>6, l = tid&63, g = l>>4, lj = l&15;

    int bid = blockIdx.x;
    int xcd = bid & 7, idx = bid >> 3;
    int z1 = xcd*ZPX + idx/NT2;
    int t2 = idx - (idx/NT2)*NT2;
    int r0 = t2*8;

    if (KIND != 2) { if (tid < 128) sst[tid] = 0.f; __syncthreads(); }

    const int s1c = (KIND==2) ? 2*z1 : z1;
    int i2b[4], i3b[4], baddr[4], ovox[4];
    #pragma unroll
    for (int t=0;t<4;t++){
        int o2 = r0 + (w<<1) + (t>>1);
        int o3 = ((t&1)<<4) + lj;
        int s2 = (KIND==2) ? (o2<<1) : o2;
        i2b[t] = s2;
        i3b[t] = o3;
        baddr[t] = ((s1c*ND2 + s2)*ND3 + o3)*CIN + g*8;
        ovox[t]  = (KIND==2) ? ((z1*OD2 + o2)*OD3 + o3)
                             : ((z1*ND2 + o2)*ND3 + o3);
    }
    const int woff = lj*32 + g*8;

    f32x4 acc[4][4];
    #pragma unroll
    for (int a=0;a<4;a++)
        #pragma unroll
        for (int b=0;b<4;b++)
            #pragma unroll
            for (int q=0;q<4;q++) acc[a][b][q] = 0.f;

    #pragma unroll 1
    for (int kd=0; kd<KD; kd++) {
        #pragma unroll
        for (int kh=0; kh<KH; kh++) {
            #pragma unroll
            for (int kw=0; kw<3; kw++) {
                const int d1 = (KIND==1) ? 0 : (kd-1);
                const int d2 = (KIND==0) ? 0 : (kh-1);
                const int d3 = kw-1;
                const bool ok1 = ((unsigned)(s1c + d1) < (unsigned)ND1);
                bool pred[4];
                #pragma unroll
                for (int t=0;t<4;t++){
                    bool ok2 = ((unsigned)(i2b[t] + d2) < (unsigned)ND2);
                    bool ok3 = ((unsigned)(i3b[t] + d3) < (unsigned)ND3);
                    pred[t] = ok1 && ok2 && ok3;
                }
                const int offsp = ((d1*ND2 + d2)*ND3 + d3)*CIN;
                const int tap = (kd*KH + kh)*3 + kw;
                #pragma unroll
                for (int ch=0; ch<NCH; ch++){
                    const int kc = tap*NCH + ch;
                    const unsigned short* wp = Wt + (size_t)kc*2048 + woff;
                    short8 av[4];
                    #pragma unroll
                    for (int ct=0; ct<4; ct++)
                        av[ct] = *reinterpret_cast<const short8*>(wp + ct*512);
                    const int off = offsp + ch*32;
                    #pragma unroll
                    for (int t=0;t<4;t++){
                        short8 bv;
                        #pragma unroll
                        for (int q=0;q<8;q++) bv[q] = 0;
                        if (pred[t]) bv = *reinterpret_cast<const short8*>(in + baddr[t] + off);
                        #pragma unroll
                        for (int ct=0; ct<4; ct++)
                            acc[ct][t] = __builtin_amdgcn_mfma_f32_16x16x32_bf16(av[ct], bv, acc[ct][t], 0,0,0);
                    }
                }
            }
        }
    }

    if (KIND == 2) {
        #pragma unroll
        for (int t=0;t<4;t++){
            float om = mout[ovox[t]];
            #pragma unroll
            for (int ct=0;ct<4;ct++){
                #pragma unroll
                for (int r=0;r<4;r++){
                    int co = ct*16 + g*4 + r;
                    outf[(size_t)co*OSP + ovox[t]] = acc[ct][t][r]*om;
                }
            }
        }
        return;
    }

    float mm[4];
    #pragma unroll
    for (int t=0;t<4;t++) mm[t] = mout[ovox[t]];
    #pragma unroll
    for (int ct=0;ct<4;ct++){
        float s1[4] = {0.f,0.f,0.f,0.f};
        float s2[4] = {0.f,0.f,0.f,0.f};
        #pragma unroll
        for (int t=0;t<4;t++){
            float v[4];
            #pragma unroll
            for (int r=0;r<4;r++){
                float xv = acc[ct][t][r]*mm[t];
                xv = (xv >= 0.f) ? xv : 0.01f*xv;
                v[r] = xv; s1[r] += xv; s2[r] += xv*xv;
            }
            unsigned lo = f2b(v[0]) | ((unsigned)f2b(v[1])<<16);
            unsigned hi = f2b(v[2]) | ((unsigned)f2b(v[3])<<16);
            uint2 pk = make_uint2(lo, hi);
            *reinterpret_cast<uint2*>(outb + (size_t)ovox[t]*64 + ct*16 + g*4) = pk;
        }
        #pragma unroll
        for (int r=0;r<4;r++){
            float a = s1[r], b = s2[r];
            a += __shfl_xor(a,1); b += __shfl_xor(b,1);
            a += __shfl_xor(a,2); b += __shfl_xor(b,2);
            a += __shfl_xor(a,4); b += __shfl_xor(b,4);
            a += __shfl_xor(a,8); b += __shfl_xor(b,8);
            if (lj == 0){
                atomicAdd(&sst[ct*16 + g*4 + r], a);
                atomicAdd(&sst[64 + ct*16 + g*4 + r], b);
            }
        }
    }
    __syncthreads();
    if (tid < 128) atomicAdd(&statsg[tid], sst[tid]);
}

// ---------------- launch ----------------
extern "C" void kernel_launch(void* const* d_in, const int* in_sizes, int n_in,
                              void* d_out, int out_size, void* d_ws, size_t ws_size,
                              hipStream_t stream)
{
    const float* x      = (const float*)d_in[0];
    const void*  mraw   = d_in[1];
    const float* W_A1   = (const float*)d_in[2];
    const float* W_A2   = (const float*)d_in[3];
    const float* W_B1   = (const float*)d_in[4];
    const float* W_B2   = (const float*)d_in[5];
    const float* W_pool = (const float*)d_in[6];
    const float* g_A1 = (const float*)d_in[7],  *b_A1 = (const float*)d_in[8];
    const float* g_A2 = (const float*)d_in[9],  *b_A2 = (const float*)d_in[10];
    const float* g_B1 = (const float*)d_in[11], *b_B1 = (const float*)d_in[12];
    const float* g_B2 = (const float*)d_in[13], *b_B2 = (const float*)d_in[14];

    char* p = (char*)d_ws;
    float* m     = (float*)p; p += (size_t)SP*4;
    float* omask = (float*)p; p += (size_t)OSP*4;
    float* stats = (float*)p; p += 4*128*4;
    float* scsh  = (float*)p; p += 4*128*4;
    float* nact  = (float*)p; p += 4;
    int*   flag  = (int*)p;   p += 4;
    p += 248;  // align to 256
    unsigned short* WtA1 = (unsigned short*)p; p += 288*64*2;
    unsigned short* WtA2 = (unsigned short*)p; p += 576*64*2;
    unsigned short* WtB1 = (unsigned short*)p; p += 288*64*2;
    unsigned short* WtB2 = (unsigned short*)p; p += 576*64*2;
    unsigned short* WtP  = (unsigned short*)p; p += 1728*64*2;
    unsigned short* X = (unsigned short*)p; p += (size_t)SP*32*2;
    unsigned short* P = (unsigned short*)p; p += (size_t)SP*64*2;
    unsigned short* Q = (unsigned short*)p; p += (size_t)SP*64*2;
    unsigned short* R = (unsigned short*)p; p += (size_t)SP*64*2;

    float* down = (float*)d_out;                 // [64][OSP]
    float* resf = down + (size_t)CO*OSP;         // [64][SP]

    hipMemsetAsync(stats, 0, 4*128*4*2 + 8, stream);   // stats+scsh+nact+flag
    k_detect<<<256, 256, 0, stream>>>((const unsigned char*)mraw, flag);
    k_mask<<<SP/256, 256, 0, stream>>>(mraw, flag, m, nact);
    k_outmask<<<OSP/256, 256, 0, stream>>>(m, omask);
    k_prep_x<<<SP/64, 256, 0, stream>>>(x, m, X);

    k_wprep<<<(64*288+255)/256, 256, 0, stream>>>(W_A1, WtA1, 32, 9);
    k_wprep<<<(64*576+255)/256, 256, 0, stream>>>(W_A2, WtA2, 64, 9);
    k_wprep<<<(64*288+255)/256, 256, 0, stream>>>(W_B1, WtB1, 32, 9);
    k_wprep<<<(64*576+255)/256, 256, 0, stream>>>(W_B2, WtB2, 64, 9);
    k_wprep<<<(64*1728+255)/256, 256, 0, stream>>>(W_pool, WtP, 64, 27);

    // A1: (3,1,3) on xs
    mconv<0,32><<<3200, 256, 0, stream>>>(X, WtA1, m, P, nullptr, stats + 0);
    k_finalize<<<1, 64, 0, stream>>>(stats + 0, stats + 64, nact, g_A1, b_A1, scsh + 0);
    k_affine<<<SP*8/256, 256, 0, stream>>>(P, scsh + 0, m);
    // A2: (1,3,3) on BN_A1 out
    mconv<1,64><<<3200, 256, 0, stream>>>(P, WtA2, m, R, nullptr, stats + 128);
    k_finalize<<<1, 64, 0, stream>>>(stats + 128, stats + 192, nact, g_A2, b_A2, scsh + 128);
    // B1: (1,3,3) on xs
    mconv<1,32><<<3200, 256, 0, stream>>>(X, WtB1, m, Q, nullptr, stats + 256);
    k_finalize<<<1, 64, 0, stream>>>(stats + 256, stats + 320, nact, g_B1, b_B1, scsh + 256);
    k_affine<<<SP*8/256, 256, 0, stream>>>(Q, scsh + 256, m);
    // B2: (3,1,3) on BN_B1 out
    mconv<0,64><<<3200, 256, 0, stream>>>(Q, WtB2, m, P, nullptr, stats + 384);
    k_finalize<<<1, 64, 0, stream>>>(stats + 384, stats + 448, nact, g_B2, b_B2, scsh + 384);
    // res_B combine -> d_out resf (f32 channel-major) + Q (bf16 channel-last for pool)
    k_resB<<<SP/64, 256, 0, stream>>>(R, P, scsh + 128, scsh + 384, m, Q, resf);
    // pool
    mconv<2,64><<<800, 256, 0, stream>>>(Q, WtP, omask, nullptr, down, nullptr);
}

// Round 3
// 895.907 us; speedup vs baseline: 8.2669x; 1.3271x over previous
//
#include <hip/hip_runtime.h>

static constexpr int ND1=160, ND2=160, ND3=32;
static constexpr int SP  = ND1*ND2*ND3;        // 819200
static constexpr int CO  = 64;
static constexpr int OD1=80, OD2=80, OD3=32;
static constexpr int OSP = OD1*OD2*OD3;        // 204800

typedef __attribute__((ext_vector_type(8))) short  short8;
typedef __attribute__((ext_vector_type(4))) float  f32x4;

__device__ __forceinline__ float b2f(unsigned u){ return __uint_as_float(u<<16); }
__device__ __forceinline__ unsigned short f2b(float f){
    unsigned u = __float_as_uint(f);
    u += 0x7fffu + ((u>>16)&1u);
    return (unsigned short)(u>>16);
}

// ---------------- mask dtype detection ----------------
__global__ void k_detect(const unsigned char* __restrict__ mb, int* __restrict__ flag)
{
    __shared__ int lf;
    if (threadIdx.x == 0) lf = 0;
    __syncthreads();
    int f = 0;
    for (int i = blockIdx.x*256 + threadIdx.x; i < SP; i += gridDim.x*256) {
        unsigned char b = mb[i];
        if (b > 1) f |= 4;
        if (b != 0 && (i & 3)) f |= 1;
    }
    if (f) atomicOr(&lf, f);
    __syncthreads();
    if (threadIdx.x == 0 && lf) atomicOr(flag, lf);
}

__global__ void k_mask(const void* __restrict__ mraw, const int* __restrict__ flag,
                       float* __restrict__ m, float* __restrict__ nact)
{
    int i = blockIdx.x*256 + threadIdx.x;
    int f = *flag;
    float v;
    if (f & 4)      v = (reinterpret_cast<const float*>(mraw)[i] != 0.f) ? 1.f : 0.f;
    else if (f & 1) v = (reinterpret_cast<const unsigned char*>(mraw)[i] != 0) ? 1.f : 0.f;
    else            v = (reinterpret_cast<const int*>(mraw)[i] != 0) ? 1.f : 0.f;
    m[i] = v;
    float s = v;
    #pragma unroll
    for (int off = 32; off > 0; off >>= 1) s += __shfl_xor(s, off);
    __shared__ float wsum[4];
    if ((threadIdx.x & 63) == 0) wsum[threadIdx.x >> 6] = s;
    __syncthreads();
    if (threadIdx.x == 0) atomicAdd(nact, wsum[0]+wsum[1]+wsum[2]+wsum[3]);
}

__global__ void k_outmask(const float* __restrict__ m, float* __restrict__ om)
{
    int i = blockIdx.x*256 + threadIdx.x;   // < OSP
    int o3 = i & 31; int t = i >> 5; int o2 = t % OD2; int o1 = t / OD2;
    float s = 0.f;
    for (int kd = 0; kd < 3; kd++) { int d1 = 2*o1 - 1 + kd; if ((unsigned)d1 >= ND1) continue;
      for (int kh = 0; kh < 3; kh++) { int d2 = 2*o2 - 1 + kh; if ((unsigned)d2 >= ND2) continue;
        for (int kw = 0; kw < 3; kw++) { int d3 = o3 - 1 + kw; if ((unsigned)d3 >= ND3) continue;
          s += m[(d1*ND2 + d2)*ND3 + d3];
        } } }
    om[i] = (s > 0.f) ? 1.f : 0.f;
}

// ---------------- BN finalize ----------------
__global__ void k_finalize(const float* __restrict__ s1, const float* __restrict__ s2,
                           const float* __restrict__ nact,
                           const float* __restrict__ g, const float* __restrict__ b,
                           float* __restrict__ scsh)
{
    int c = threadIdx.x;      // 64 threads
    float n = *nact;
    float mean = s1[c] / n;
    float var  = s2[c] / n - mean*mean;
    float inv  = rsqrtf(var + 1e-5f);
    float sc   = inv * g[c];
    scsh[c]      = sc;
    scsh[64 + c] = b[c] - mean*sc;
}

// ---------------- weight pre-pack: W[co][ci][tap] f32 -> Wt[kc][co][32] bf16 ----------------
__global__ void k_wprep(const float* __restrict__ W, unsigned short* __restrict__ Wt,
                        int CIN, int NT)
{
    int i = blockIdx.x*256 + threadIdx.x;
    int K = CIN*NT;
    if (i >= 64*K) return;
    int ksub = i & 31;
    int t = i >> 5;
    int co = t & 63;
    int kc = t >> 6;
    int nch = CIN >> 5;
    int tap = kc / nch;
    int ci  = (kc - tap*nch)*32 + ksub;
    Wt[i] = f2b(W[((size_t)co*CIN + ci)*NT + tap]);
}

// ---------------- x f32 [ci][sp] -> masked bf16 [sp][32] (tiled transpose) ----------------
__global__ void k_prep_x(const float* __restrict__ x, const float* __restrict__ m,
                         unsigned short* __restrict__ xt)
{
    __shared__ float t[64][33];
    int sp0 = blockIdx.x*64;
    int tid = threadIdx.x;
    int c = tid>>6, s = tid&63;
    float mm = m[sp0+s];
    #pragma unroll
    for (int r=0;r<8;r++){
        int ci = c + r*4;
        t[s][ci] = x[(size_t)ci*SP + sp0 + s]*mm;
    }
    __syncthreads();
    int sp = tid>>2, c0 = (tid&3)*8;
    unsigned short o[8];
    #pragma unroll
    for (int i=0;i<8;i++) o[i] = f2b(t[sp][c0+i]);
    uint4 pk;
    pk.x = o[0] | ((unsigned)o[1]<<16);
    pk.y = o[2] | ((unsigned)o[3]<<16);
    pk.z = o[4] | ((unsigned)o[5]<<16);
    pk.w = o[6] | ((unsigned)o[7]<<16);
    *reinterpret_cast<uint4*>(xt + (size_t)(sp0+sp)*32 + c0) = pk;
}

// ---------------- res_B combine ----------------
__global__ void k_resB(const unsigned short* __restrict__ hA, const unsigned short* __restrict__ hB,
                       const float* __restrict__ sA, const float* __restrict__ sB,
                       const float* __restrict__ m,
                       unsigned short* __restrict__ rbt, float* __restrict__ resf)
{
    __shared__ float t[64][65];
    __shared__ float ss[256];
    int tid = threadIdx.x;
    if (tid < 128){ ss[tid] = sA[tid]; ss[128+tid] = sB[tid]; }
    __syncthreads();
    int sp0 = blockIdx.x*64;
    int sp = tid>>2, c0 = (tid&3)*16;
    float mm = m[sp0+sp];
    const size_t base = (size_t)(sp0+sp)*64 + c0;
    uint4 a0 = *reinterpret_cast<const uint4*>(hA + base);
    uint4 a1 = *reinterpret_cast<const uint4*>(hA + base + 8);
    uint4 b0 = *reinterpret_cast<const uint4*>(hB + base);
    uint4 b1 = *reinterpret_cast<const uint4*>(hB + base + 8);
    unsigned ua[16] = {a0.x&0xffffu,a0.x>>16,a0.y&0xffffu,a0.y>>16,a0.z&0xffffu,a0.z>>16,a0.w&0xffffu,a0.w>>16,
                       a1.x&0xffffu,a1.x>>16,a1.y&0xffffu,a1.y>>16,a1.z&0xffffu,a1.z>>16,a1.w&0xffffu,a1.w>>16};
    unsigned ub[16] = {b0.x&0xffffu,b0.x>>16,b0.y&0xffffu,b0.y>>16,b0.z&0xffffu,b0.z>>16,b0.w&0xffffu,b0.w>>16,
                       b1.x&0xffffu,b1.x>>16,b1.y&0xffffu,b1.y>>16,b1.z&0xffffu,b1.z>>16,b1.w&0xffffu,b1.w>>16};
    unsigned short o[16];
    #pragma unroll
    for (int q=0;q<16;q++){
        int ci = c0+q;
        float v = (b2f(ua[q])*ss[ci] + ss[64+ci] + b2f(ub[q])*ss[128+ci] + ss[192+ci])*mm;
        t[sp][ci] = v;
        o[q] = f2b(v);
    }
    uint4 p0, p1;
    p0.x = o[0]|((unsigned)o[1]<<16);  p0.y = o[2]|((unsigned)o[3]<<16);
    p0.z = o[4]|((unsigned)o[5]<<16);  p0.w = o[6]|((unsigned)o[7]<<16);
    p1.x = o[8]|((unsigned)o[9]<<16);  p1.y = o[10]|((unsigned)o[11]<<16);
    p1.z = o[12]|((unsigned)o[13]<<16); p1.w = o[14]|((unsigned)o[15]<<16);
    *reinterpret_cast<uint4*>(rbt + base)     = p0;
    *reinterpret_cast<uint4*>(rbt + base + 8) = p1;
    __syncthreads();
    int ci = tid>>2, s0 = (tid&3)*16;
    #pragma unroll
    for (int kq=0;kq<4;kq++){
        float4 ov;
        ov.x = t[s0+4*kq+0][ci]; ov.y = t[s0+4*kq+1][ci];
        ov.z = t[s0+4*kq+2][ci]; ov.w = t[s0+4*kq+3][ci];
        *reinterpret_cast<float4*>(resf + (size_t)ci*SP + sp0 + s0 + 4*kq) = ov;
    }
}

// ---------------- MFMA conv with LDS-staged input ----------------
// KIND 0: taps (3,1,3) rows=d1 fixed d2 ; KIND 1: taps (1,3,3) rows=d2 fixed d1
// KIND 2: pool 3x3x3 stride (2,2,1): rows=d2 (9 staged), per-d1-plane restage
template<int KIND, int CIN, bool HASAFF>
__launch_bounds__(256, 3)
__global__ void mconv2(const unsigned short* __restrict__ in,   // bf16 [vox][CIN]
                       const unsigned short* __restrict__ Wt,   // bf16 [kc][64co][32k]
                       const float* __restrict__ scsh,          // affine (HASAFF)
                       const float* __restrict__ mstage,        // mask for staging (HASAFF)
                       const float* __restrict__ mout,          // mask at output voxel
                       unsigned short* __restrict__ outb,       // bf16 [vox][64] (KIND 0/1)
                       float* __restrict__ outf,                // f32 [co][OSP]  (KIND 2)
                       float* __restrict__ statsg)
{
    constexpr int NCH  = CIN/32;
    constexpr int NR   = (KIND==2) ? 9 : 10;
    constexpr int ROWB = 34*CIN*2;
    constexpr int SWZ  = (CIN==64) ? 7 : 3;
    __shared__ __align__(16) char lds[NR*ROWB];
    __shared__ float sst[128];

    const int tid = threadIdx.x;
    const int w = tid>>6, l = tid&63, g = l>>4, lj = l&15;

    int gi = (blockIdx.x & 7)*(gridDim.x>>3) + (blockIdx.x>>3);
    int z, r0;
    if (KIND==2){ z = gi % OD1; r0 = (gi / OD1)*4; }
    else        { z = gi % 160; r0 = (gi / 160)*8; }

    if (KIND != 2) { if (tid < 128) sst[tid] = 0.f; }

    // staging thread mapping
    const int sd3 = tid>>3;              // 0..31
    const int k0  = (tid&7)*(CIN/8);     // elem offset (8 for CIN64, 4 for CIN32)

    float sc[8], sh[8];
    if (HASAFF){
        #pragma unroll
        for (int j=0;j<8;j++){ sc[j]=scsh[k0+j]; sh[j]=scsh[64+k0+j]; }
    }

    // ---- stage (KIND 0/1: once) ----
    if (KIND != 2){
        #pragma unroll 1
        for (int rr=0; rr<NR; rr++){
            int rw = r0 - 1 + rr;
            bool ok = ((unsigned)rw < 160u);
            int dst = rr*ROWB + (((sd3+1)*CIN + k0)*2);
            dst ^= (((sd3+1)&SWZ)<<4);
            if (CIN==64){
                uint4 v = make_uint4(0,0,0,0);
                if (ok){
                    int vox = (KIND==0) ? ((rw*ND2 + z)*ND3 + sd3)
                                        : ((z*ND2 + rw)*ND3 + sd3);
                    v = *reinterpret_cast<const uint4*>(in + (size_t)vox*CIN + k0);
                    if (HASAFF){
                        float mm = mstage[vox];
                        unsigned us[8] = {v.x&0xffffu,v.x>>16,v.y&0xffffu,v.y>>16,
                                          v.z&0xffffu,v.z>>16,v.w&0xffffu,v.w>>16};
                        unsigned short o[8];
                        #pragma unroll
                        for (int j=0;j<8;j++) o[j] = f2b((b2f(us[j])*sc[j]+sh[j])*mm);
                        v.x = o[0]|((unsigned)o[1]<<16); v.y = o[2]|((unsigned)o[3]<<16);
                        v.z = o[4]|((unsigned)o[5]<<16); v.w = o[6]|((unsigned)o[7]<<16);
                    }
                }
                *reinterpret_cast<uint4*>(lds + dst) = v;
            } else {
                uint2 v = make_uint2(0,0);
                if (ok){
                    int vox = (KIND==0) ? ((rw*ND2 + z)*ND3 + sd3)
                                        : ((z*ND2 + rw)*ND3 + sd3);
                    v = *reinterpret_cast<const uint2*>(in + (size_t)vox*CIN + k0);
                }
                *reinterpret_cast<uint2*>(lds + dst) = v;
            }
        }
        // border slots 0 and 33
        for (int i = tid; i < NR*2*(CIN/8); i += 256){
            int per = CIN/8;
            int rr = i / (2*per);
            int rem = i - rr*2*per;
            int slot = (rem >= per) ? 33 : 0;
            int kc16 = (rem >= per) ? (rem - per) : rem;
            int dst = rr*ROWB + slot*CIN*2 + kc16*16;
            dst ^= ((slot&SWZ)<<4);
            *reinterpret_cast<uint4*>(lds + dst) = make_uint4(0,0,0,0);
        }
        __syncthreads();
    }

    // per-t read bases and swizzles
    int swz[3];
    #pragma unroll
    for (int kw=0;kw<3;kw++) swz[kw] = ((lj+kw)&SWZ)<<4;
    const int woff = lj*32 + g*8;

    if (KIND != 2){
        int tb[4];
        #pragma unroll
        for (int t=0;t<4;t++){
            int rowb = w*2 + (t>>1);
            int o3   = (t&1)*16 + lj;
            tb[t] = rowb*ROWB + ((o3*CIN + g*8)*2);
        }
        f32x4 acc[4][4];
        #pragma unroll
        for (int a=0;a<4;a++)
            #pragma unroll
            for (int b=0;b<4;b++)
                #pragma unroll
                for (int q=0;q<4;q++) acc[a][b][q] = 0.f;

        #pragma unroll 1
        for (int ch=0; ch<NCH; ch++){
            #pragma unroll
            for (int tap=0; tap<9; tap++){
                const int kd = tap/3, kw = tap - kd*3;
                const unsigned short* wp = Wt + (size_t)(tap*NCH+ch)*2048 + woff;
                short8 av[4];
                #pragma unroll
                for (int ct=0; ct<4; ct++)
                    av[ct] = *reinterpret_cast<const short8*>(wp + ct*512);
                const int tapoff = kd*ROWB + (kw*CIN + ch*32)*2;
                #pragma unroll
                for (int t=0;t<4;t++){
                    int off = (tb[t] + tapoff) ^ swz[kw];
                    short8 bv = *reinterpret_cast<const short8*>(lds + off);
                    #pragma unroll
                    for (int ct=0; ct<4; ct++)
                        acc[ct][t] = __builtin_amdgcn_mfma_f32_16x16x32_bf16(av[ct], bv, acc[ct][t], 0,0,0);
                }
            }
        }

        // epilogue
        int ovox[4];
        #pragma unroll
        for (int t=0;t<4;t++){
            int o2r = r0 + w*2 + (t>>1);
            int o3  = (t&1)*16 + lj;
            ovox[t] = (KIND==0) ? ((o2r*ND2 + z)*ND3 + o3)
                                : ((z*ND2 + o2r)*ND3 + o3);
        }
        float mm[4];
        #pragma unroll
        for (int t=0;t<4;t++) mm[t] = mout[ovox[t]];
        __syncthreads();   // sst init visible
        #pragma unroll
        for (int ct=0;ct<4;ct++){
            float s1[4] = {0.f,0.f,0.f,0.f};
            float s2[4] = {0.f,0.f,0.f,0.f};
            #pragma unroll
            for (int t=0;t<4;t++){
                float v[4];
                #pragma unroll
                for (int r=0;r<4;r++){
                    float xv = acc[ct][t][r]*mm[t];
                    xv = (xv >= 0.f) ? xv : 0.01f*xv;
                    v[r] = xv; s1[r] += xv; s2[r] += xv*xv;
                }
                unsigned lo = f2b(v[0]) | ((unsigned)f2b(v[1])<<16);
                unsigned hi = f2b(v[2]) | ((unsigned)f2b(v[3])<<16);
                *reinterpret_cast<uint2*>(outb + (size_t)ovox[t]*64 + ct*16 + g*4) = make_uint2(lo,hi);
            }
            #pragma unroll
            for (int r=0;r<4;r++){
                float a = s1[r], b = s2[r];
                a += __shfl_xor(a,1); b += __shfl_xor(b,1);
                a += __shfl_xor(a,2); b += __shfl_xor(b,2);
                a += __shfl_xor(a,4); b += __shfl_xor(b,4);
                a += __shfl_xor(a,8); b += __shfl_xor(b,8);
                if (lj == 0){
                    atomicAdd(&sst[ct*16 + g*4 + r], a);
                    atomicAdd(&sst[64 + ct*16 + g*4 + r], b);
                }
            }
        }
        __syncthreads();
        if (tid < 128) atomicAdd(&statsg[tid], sst[tid]);
        return;
    }

    // ---- KIND 2: pool ----
    if (KIND == 2){
        int tb2[2];
        #pragma unroll
        for (int t=0;t<2;t++){
            int o3 = t*16 + lj;
            tb2[t] = (o3*64 + g*8)*2;
        }
        f32x4 acc[4][2];
        #pragma unroll
        for (int a=0;a<4;a++)
            #pragma unroll
            for (int b=0;b<2;b++)
                #pragma unroll
                for (int q=0;q<4;q++) acc[a][b][q] = 0.f;

        #pragma unroll 1
        for (int kd=0; kd<3; kd++){
            __syncthreads();
            // stage plane d1 = 2z-1+kd: rows d2 = 2*r0-1+rr, rr 0..8
            int d1 = 2*z - 1 + kd;
            bool pok = ((unsigned)d1 < (unsigned)ND1);
            #pragma unroll 1
            for (int rr=0; rr<9; rr++){
                int d2 = 2*r0 - 1 + rr;
                bool ok = pok && ((unsigned)d2 < (unsigned)ND2);
                int dst = rr*ROWB + (((sd3+1)*64 + k0)*2);
                dst ^= (((sd3+1)&7)<<4);
                uint4 v = make_uint4(0,0,0,0);
                if (ok){
                    int vox = (d1*ND2 + d2)*ND3 + sd3;
                    v = *reinterpret_cast<const uint4*>(in + (size_t)vox*64 + k0);
                }
                *reinterpret_cast<uint4*>(lds + dst) = v;
            }
            for (int i = tid; i < 9*2*8; i += 256){
                int rr = i / 16;
                int rem = i - rr*16;
                int slot = (rem >= 8) ? 33 : 0;
                int kc16 = rem & 7;
                int dst = rr*ROWB + slot*128 + kc16*16;
                dst ^= ((slot&7)<<4);
                *reinterpret_cast<uint4*>(lds + dst) = make_uint4(0,0,0,0);
            }
            __syncthreads();
            #pragma unroll 1
            for (int ch=0; ch<2; ch++){
                #pragma unroll
                for (int tap=0; tap<9; tap++){
                    const int kh = tap/3, kw = tap - kh*3;
                    const int kc = ((kd*3+kh)*3+kw)*2 + ch;
                    const unsigned short* wp = Wt + (size_t)kc*2048 + woff;
                    short8 av[4];
                    #pragma unroll
                    for (int ct=0; ct<4; ct++)
                        av[ct] = *reinterpret_cast<const short8*>(wp + ct*512);
                    const int rr = 2*w + kh;
                    const int tapoff = rr*ROWB + (kw*64 + ch*32)*2;
                    #pragma unroll
                    for (int t=0;t<2;t++){
                        int off = (tb2[t] + tapoff) ^ swz[kw];
                        short8 bv = *reinterpret_cast<const short8*>(lds + off);
                        #pragma unroll
                        for (int ct=0; ct<4; ct++)
                            acc[ct][t] = __builtin_amdgcn_mfma_f32_16x16x32_bf16(av[ct], bv, acc[ct][t], 0,0,0);
                    }
                }
            }
        }
        // epilogue
        #pragma unroll
        for (int t=0;t<2;t++){
            int o2 = r0 + w;
            int o3 = t*16 + lj;
            int ovox = (z*OD2 + o2)*OD3 + o3;
            float om = mout[ovox];
            #pragma unroll
            for (int ct=0;ct<4;ct++){
                #pragma unroll
                for (int r=0;r<4;r++){
                    int co = ct*16 + g*4 + r;
                    outf[(size_t)co*OSP + ovox] = acc[ct][t][r]*om;
                }
            }
        }
    }
}

// ---------------- launch ----------------
extern "C" void kernel_launch(void* const* d_in, const int* in_sizes, int n_in,
                              void* d_out, int out_size, void* d_ws, size_t ws_size,
                              hipStream_t stream)
{
    const float* x      = (const float*)d_in[0];
    const void*  mraw   = d_in[1];
    const float* W_A1   = (const float*)d_in[2];
    const float* W_A2   = (const float*)d_in[3];
    const float* W_B1   = (const float*)d_in[4];
    const float* W_B2   = (const float*)d_in[5];
    const float* W_pool = (const float*)d_in[6];
    const float* g_A1 = (const float*)d_in[7],  *b_A1 = (const float*)d_in[8];
    const float* g_A2 = (const float*)d_in[9],  *b_A2 = (const float*)d_in[10];
    const float* g_B1 = (const float*)d_in[11], *b_B1 = (const float*)d_in[12];
    const float* g_B2 = (const float*)d_in[13], *b_B2 = (const float*)d_in[14];

    char* p = (char*)d_ws;
    float* m     = (float*)p; p += (size_t)SP*4;
    float* omask = (float*)p; p += (size_t)OSP*4;
    float* stats = (float*)p; p += 4*128*4;
    float* scsh  = (float*)p; p += 4*128*4;
    float* nact  = (float*)p; p += 4;
    int*   flag  = (int*)p;   p += 4;
    p += 248;
    unsigned short* WtA1 = (unsigned short*)p; p += 288*64*2;
    unsigned short* WtA2 = (unsigned short*)p; p += 576*64*2;
    unsigned short* WtB1 = (unsigned short*)p; p += 288*64*2;
    unsigned short* WtB2 = (unsigned short*)p; p += 576*64*2;
    unsigned short* WtP  = (unsigned short*)p; p += 1728*64*2;
    unsigned short* X = (unsigned short*)p; p += (size_t)SP*32*2;
    unsigned short* P = (unsigned short*)p; p += (size_t)SP*64*2;
    unsigned short* Q = (unsigned short*)p; p += (size_t)SP*64*2;
    unsigned short* R = (unsigned short*)p; p += (size_t)SP*64*2;

    float* down = (float*)d_out;                 // [64][OSP]
    float* resf = down + (size_t)CO*OSP;         // [64][SP]

    hipMemsetAsync(stats, 0, 4*128*4*2 + 8, stream);
    k_detect<<<256, 256, 0, stream>>>((const unsigned char*)mraw, flag);
    k_mask<<<SP/256, 256, 0, stream>>>(mraw, flag, m, nact);
    k_outmask<<<OSP/256, 256, 0, stream>>>(m, omask);
    k_prep_x<<<SP/64, 256, 0, stream>>>(x, m, X);

    k_wprep<<<(64*288+255)/256, 256, 0, stream>>>(W_A1, WtA1, 32, 9);
    k_wprep<<<(64*576+255)/256, 256, 0, stream>>>(W_A2, WtA2, 64, 9);
    k_wprep<<<(64*288+255)/256, 256, 0, stream>>>(W_B1, WtB1, 32, 9);
    k_wprep<<<(64*576+255)/256, 256, 0, stream>>>(W_B2, WtB2, 64, 9);
    k_wprep<<<(64*1728+255)/256, 256, 0, stream>>>(W_pool, WtP, 64, 27);

    // A1: (3,1,3) on xs
    mconv2<0,32,false><<<3200, 256, 0, stream>>>(X, WtA1, nullptr, nullptr, m, P, nullptr, stats + 0);
    k_finalize<<<1, 64, 0, stream>>>(stats + 0, stats + 64, nact, g_A1, b_A1, scsh + 0);
    // A2: (1,3,3) on BN_A1(P) — affine fused into staging
    mconv2<1,64,true><<<3200, 256, 0, stream>>>(P, WtA2, scsh + 0, m, m, R, nullptr, stats + 128);
    k_finalize<<<1, 64, 0, stream>>>(stats + 128, stats + 192, nact, g_A2, b_A2, scsh + 128);
    // B1: (1,3,3) on xs
    mconv2<1,32,false><<<3200, 256, 0, stream>>>(X, WtB1, nullptr, nullptr, m, Q, nullptr, stats + 256);
    k_finalize<<<1, 64, 0, stream>>>(stats + 256, stats + 320, nact, g_B1, b_B1, scsh + 256);
    // B2: (3,1,3) on BN_B1(Q) — affine fused; raw out -> P
    mconv2<0,64,true><<<3200, 256, 0, stream>>>(Q, WtB2, scsh + 256, m, m, P, nullptr, stats + 384);
    k_finalize<<<1, 64, 0, stream>>>(stats + 384, stats + 448, nact, g_B2, b_B2, scsh + 384);
    // res_B combine -> Q (bf16 for pool) + resf (f32 output)
    k_resB<<<SP/64, 256, 0, stream>>>(R, P, scsh + 128, scsh + 384, m, Q, resf);
    // pool
    mconv2<2,64,false><<<1600, 256, 0, stream>>>(Q, WtP, nullptr, nullptr, omask, nullptr, down, nullptr);
}

// Round 4
// 890.892 us; speedup vs baseline: 8.3135x; 1.0056x over previous
//
#include <hip/hip_runtime.h>

static constexpr int ND1=160, ND2=160, ND3=32;
static constexpr int SP  = ND1*ND2*ND3;        // 819200
static constexpr int CO  = 64;
static constexpr int OD1=80, OD2=80, OD3=32;
static constexpr int OSP = OD1*OD2*OD3;        // 204800

typedef __attribute__((ext_vector_type(8))) short  short8;
typedef __attribute__((ext_vector_type(4))) float  f32x4;

__device__ __forceinline__ float b2f(unsigned u){ return __uint_as_float(u<<16); }
__device__ __forceinline__ unsigned short f2b(float f){
    unsigned u = __float_as_uint(f);
    u += 0x7fffu + ((u>>16)&1u);
    return (unsigned short)(u>>16);
}

// ---------------- mask dtype detection ----------------
__global__ void k_detect(const unsigned char* __restrict__ mb, int* __restrict__ flag)
{
    __shared__ int lf;
    if (threadIdx.x == 0) lf = 0;
    __syncthreads();
    int f = 0;
    for (int i = blockIdx.x*256 + threadIdx.x; i < SP; i += gridDim.x*256) {
        unsigned char b = mb[i];
        if (b > 1) f |= 4;
        if (b != 0 && (i & 3)) f |= 1;
    }
    if (f) atomicOr(&lf, f);
    __syncthreads();
    if (threadIdx.x == 0 && lf) atomicOr(flag, lf);
}

__global__ void k_mask(const void* __restrict__ mraw, const int* __restrict__ flag,
                       float* __restrict__ m, float* __restrict__ nact)
{
    int i = blockIdx.x*256 + threadIdx.x;
    int f = *flag;
    float v;
    if (f & 4)      v = (reinterpret_cast<const float*>(mraw)[i] != 0.f) ? 1.f : 0.f;
    else if (f & 1) v = (reinterpret_cast<const unsigned char*>(mraw)[i] != 0) ? 1.f : 0.f;
    else            v = (reinterpret_cast<const int*>(mraw)[i] != 0) ? 1.f : 0.f;
    m[i] = v;
    float s = v;
    #pragma unroll
    for (int off = 32; off > 0; off >>= 1) s += __shfl_xor(s, off);
    __shared__ float wsum[4];
    if ((threadIdx.x & 63) == 0) wsum[threadIdx.x >> 6] = s;
    __syncthreads();
    if (threadIdx.x == 0) atomicAdd(nact, wsum[0]+wsum[1]+wsum[2]+wsum[3]);
}

__global__ void k_outmask(const float* __restrict__ m, float* __restrict__ om)
{
    int i = blockIdx.x*256 + threadIdx.x;   // < OSP
    int o3 = i & 31; int t = i >> 5; int o2 = t % OD2; int o1 = t / OD2;
    float s = 0.f;
    for (int kd = 0; kd < 3; kd++) { int d1 = 2*o1 - 1 + kd; if ((unsigned)d1 >= ND1) continue;
      for (int kh = 0; kh < 3; kh++) { int d2 = 2*o2 - 1 + kh; if ((unsigned)d2 >= ND2) continue;
        for (int kw = 0; kw < 3; kw++) { int d3 = o3 - 1 + kw; if ((unsigned)d3 >= ND3) continue;
          s += m[(d1*ND2 + d2)*ND3 + d3];
        } } }
    om[i] = (s > 0.f) ? 1.f : 0.f;
}

// ---------------- BN finalize ----------------
__global__ void k_finalize(const float* __restrict__ s1, const float* __restrict__ s2,
                           const float* __restrict__ nact,
                           const float* __restrict__ g, const float* __restrict__ b,
                           float* __restrict__ scsh)
{
    int c = threadIdx.x;      // 64 threads
    float n = *nact;
    float mean = s1[c] / n;
    float var  = s2[c] / n - mean*mean;
    float inv  = rsqrtf(var + 1e-5f);
    float sc   = inv * g[c];
    scsh[c]      = sc;
    scsh[64 + c] = b[c] - mean*sc;
}

// ---------------- weight pre-pack: W[co][ci][tap] f32 -> Wt[kc][co][32] bf16 ----------------
__global__ void k_wprep(const float* __restrict__ W, unsigned short* __restrict__ Wt,
                        int CIN, int NT)
{
    int i = blockIdx.x*256 + threadIdx.x;
    int K = CIN*NT;
    if (i >= 64*K) return;
    int ksub = i & 31;
    int t = i >> 5;
    int co = t & 63;
    int kc = t >> 6;
    int nch = CIN >> 5;
    int tap = kc / nch;
    int ci  = (kc - tap*nch)*32 + ksub;
    Wt[i] = f2b(W[((size_t)co*CIN + ci)*NT + tap]);
}

// ---------------- x f32 [ci][sp] -> masked bf16 [sp][32] ----------------
__global__ void k_prep_x(const float* __restrict__ x, const float* __restrict__ m,
                         unsigned short* __restrict__ xt)
{
    __shared__ float t[64][33];
    int sp0 = blockIdx.x*64;
    int tid = threadIdx.x;
    int c = tid>>6, s = tid&63;
    float mm = m[sp0+s];
    #pragma unroll
    for (int r=0;r<8;r++){
        int ci = c + r*4;
        t[s][ci] = x[(size_t)ci*SP + sp0 + s]*mm;
    }
    __syncthreads();
    int sp = tid>>2, c0 = (tid&3)*8;
    unsigned short o[8];
    #pragma unroll
    for (int i=0;i<8;i++) o[i] = f2b(t[sp][c0+i]);
    uint4 pk;
    pk.x = o[0] | ((unsigned)o[1]<<16);
    pk.y = o[2] | ((unsigned)o[3]<<16);
    pk.z = o[4] | ((unsigned)o[5]<<16);
    pk.w = o[6] | ((unsigned)o[7]<<16);
    *reinterpret_cast<uint4*>(xt + (size_t)(sp0+sp)*32 + c0) = pk;
}

// ---------------- res_B combine ----------------
__global__ void k_resB(const unsigned short* __restrict__ hA, const unsigned short* __restrict__ hB,
                       const float* __restrict__ sA, const float* __restrict__ sB,
                       const float* __restrict__ m,
                       unsigned short* __restrict__ rbt, float* __restrict__ resf)
{
    __shared__ float t[64][65];
    __shared__ float ss[256];
    int tid = threadIdx.x;
    if (tid < 128){ ss[tid] = sA[tid]; ss[128+tid] = sB[tid]; }
    __syncthreads();
    int sp0 = blockIdx.x*64;
    int sp = tid>>2, c0 = (tid&3)*16;
    float mm = m[sp0+sp];
    const size_t base = (size_t)(sp0+sp)*64 + c0;
    uint4 a0 = *reinterpret_cast<const uint4*>(hA + base);
    uint4 a1 = *reinterpret_cast<const uint4*>(hA + base + 8);
    uint4 b0 = *reinterpret_cast<const uint4*>(hB + base);
    uint4 b1 = *reinterpret_cast<const uint4*>(hB + base + 8);
    unsigned ua[16] = {a0.x&0xffffu,a0.x>>16,a0.y&0xffffu,a0.y>>16,a0.z&0xffffu,a0.z>>16,a0.w&0xffffu,a0.w>>16,
                       a1.x&0xffffu,a1.x>>16,a1.y&0xffffu,a1.y>>16,a1.z&0xffffu,a1.z>>16,a1.w&0xffffu,a1.w>>16};
    unsigned ub[16] = {b0.x&0xffffu,b0.x>>16,b0.y&0xffffu,b0.y>>16,b0.z&0xffffu,b0.z>>16,b0.w&0xffffu,b0.w>>16,
                       b1.x&0xffffu,b1.x>>16,b1.y&0xffffu,b1.y>>16,b1.z&0xffffu,b1.z>>16,b1.w&0xffffu,b1.w>>16};
    unsigned short o[16];
    #pragma unroll
    for (int q=0;q<16;q++){
        int ci = c0+q;
        float v = (b2f(ua[q])*ss[ci] + ss[64+ci] + b2f(ub[q])*ss[128+ci] + ss[192+ci])*mm;
        t[sp][ci] = v;
        o[q] = f2b(v);
    }
    uint4 p0, p1;
    p0.x = o[0]|((unsigned)o[1]<<16);  p0.y = o[2]|((unsigned)o[3]<<16);
    p0.z = o[4]|((unsigned)o[5]<<16);  p0.w = o[6]|((unsigned)o[7]<<16);
    p1.x = o[8]|((unsigned)o[9]<<16);  p1.y = o[10]|((unsigned)o[11]<<16);
    p1.z = o[12]|((unsigned)o[13]<<16); p1.w = o[14]|((unsigned)o[15]<<16);
    *reinterpret_cast<uint4*>(rbt + base)     = p0;
    *reinterpret_cast<uint4*>(rbt + base + 8) = p1;
    __syncthreads();
    int ci = tid>>2, s0 = (tid&3)*16;
    #pragma unroll
    for (int kq=0;kq<4;kq++){
        float4 ov;
        ov.x = t[s0+4*kq+0][ci]; ov.y = t[s0+4*kq+1][ci];
        ov.z = t[s0+4*kq+2][ci]; ov.w = t[s0+4*kq+3][ci];
        *reinterpret_cast<float4*>(resf + (size_t)ci*SP + sp0 + s0 + 4*kq) = ov;
    }
}

// ---------------- MFMA conv, LDS-staged, pipelined ----------------
// KIND 0: taps (3,1,3) rows=d1 ; KIND 1: taps (1,3,3) rows=d2 ; KIND 2: pool
template<int KIND, int CIN, bool HASAFF>
__launch_bounds__(256, (CIN==32 || KIND==2) ? 4 : 3)
__global__ void mconv3(const unsigned short* __restrict__ in,   // bf16 [vox][CIN]
                       const unsigned short* __restrict__ Wt,   // bf16 [kc][64co][32k]
                       const float* __restrict__ s1in,          // prev-BN stats (HASAFF)
                       const float* __restrict__ s2in,
                       const float* __restrict__ nactp,
                       const float* __restrict__ gin, const float* __restrict__ bin,
                       const float* __restrict__ mstage,
                       const float* __restrict__ mout,
                       unsigned short* __restrict__ outb,       // bf16 [vox][64] (KIND 0/1)
                       float* __restrict__ outf,                // f32 [co][OSP]  (KIND 2)
                       float* __restrict__ statsg)
{
    constexpr int NCH  = CIN/32;
    constexpr int NR   = (KIND==2) ? 9 : 10;
    constexpr int ROWB = 34*CIN*2;
    constexpr int SWZ  = (CIN==64) ? 7 : 3;
    __shared__ __align__(16) char lds[NR*ROWB];
    __shared__ float sst[128];

    const int tid = threadIdx.x;
    const int w = tid>>6, l = tid&63, g = l>>4, lj = l&15;

    int gi = (blockIdx.x & 7)*(gridDim.x>>3) + (blockIdx.x>>3);
    int z, r0;
    if (KIND==2){ z = gi % OD1; r0 = (gi / OD1)*4; }
    else        { z = gi % 160; r0 = (gi / 160)*8; }

    if (KIND != 2) { if (tid < 128) sst[tid] = 0.f; }

    const int sd3 = tid>>3;              // 0..31
    const int k0  = (tid&7)*(CIN/8);     // 8 ch (CIN64) / 4 ch (CIN32)

    float sc[8], sh[8];
    if (HASAFF){
        float n = *nactp;
        #pragma unroll
        for (int j=0;j<8;j++){
            int c = k0+j;
            float mean = s1in[c]/n;
            float var  = s2in[c]/n - mean*mean;
            float inv  = rsqrtf(var + 1e-5f);
            sc[j] = inv*gin[c];
            sh[j] = bin[c] - mean*sc[j];
        }
    }

    // ---- stage (KIND 0/1) ----
    if (KIND != 2){
        #pragma unroll 1
        for (int rr=0; rr<NR; rr++){
            int rw = r0 - 1 + rr;
            bool ok = ((unsigned)rw < 160u);
            int dst = rr*ROWB + (((sd3+1)*CIN + k0)*2);
            dst ^= (((sd3+1)&SWZ)<<4);
            if (CIN==64){
                uint4 v = make_uint4(0,0,0,0);
                if (ok){
                    int vox = (KIND==0) ? ((rw*ND2 + z)*ND3 + sd3)
                                        : ((z*ND2 + rw)*ND3 + sd3);
                    v = *reinterpret_cast<const uint4*>(in + (size_t)vox*CIN + k0);
                    if (HASAFF){
                        float mm = mstage[vox];
                        unsigned us[8] = {v.x&0xffffu,v.x>>16,v.y&0xffffu,v.y>>16,
                                          v.z&0xffffu,v.z>>16,v.w&0xffffu,v.w>>16};
                        unsigned short o[8];
                        #pragma unroll
                        for (int j=0;j<8;j++) o[j] = f2b((b2f(us[j])*sc[j]+sh[j])*mm);
                        v.x = o[0]|((unsigned)o[1]<<16); v.y = o[2]|((unsigned)o[3]<<16);
                        v.z = o[4]|((unsigned)o[5]<<16); v.w = o[6]|((unsigned)o[7]<<16);
                    }
                }
                *reinterpret_cast<uint4*>(lds + dst) = v;
            } else {
                uint2 v = make_uint2(0,0);
                if (ok){
                    int vox = (KIND==0) ? ((rw*ND2 + z)*ND3 + sd3)
                                        : ((z*ND2 + rw)*ND3 + sd3);
                    v = *reinterpret_cast<const uint2*>(in + (size_t)vox*CIN + k0);
                }
                *reinterpret_cast<uint2*>(lds + dst) = v;
            }
        }
        for (int i = tid; i < NR*2*(CIN/8); i += 256){
            int per = CIN/8;
            int rr = i / (2*per);
            int rem = i - rr*2*per;
            int slot = (rem >= per) ? 33 : 0;
            int kc16 = (rem >= per) ? (rem - per) : rem;
            int dst = rr*ROWB + slot*CIN*2 + kc16*16;
            dst ^= ((slot&SWZ)<<4);
            *reinterpret_cast<uint4*>(lds + dst) = make_uint4(0,0,0,0);
        }
        __syncthreads();
    }

    int swz[3];
    #pragma unroll
    for (int kw=0;kw<3;kw++) swz[kw] = ((lj+kw)&SWZ)<<4;
    const int woff = lj*32 + g*8;

    if (KIND != 2){
        int tb[4];
        #pragma unroll
        for (int t=0;t<4;t++){
            int rowb = w*2 + (t>>1);
            int o3   = (t&1)*16 + lj;
            tb[t] = rowb*ROWB + ((o3*CIN + g*8)*2);
        }
        f32x4 acc[4][4];
        #pragma unroll
        for (int a=0;a<4;a++)
            #pragma unroll
            for (int b=0;b<4;b++)
                #pragma unroll
                for (int q=0;q<4;q++) acc[a][b][q] = 0.f;

        short8 pa[2][4], pb[2][4];
        auto loadA = [&](int tap, int ch, int buf){
            const unsigned short* wp = Wt + (size_t)(tap*NCH+ch)*2048 + woff;
            #pragma unroll
            for (int ct=0;ct<4;ct++) pa[buf][ct] = *reinterpret_cast<const short8*>(wp + ct*512);
        };
        auto loadB = [&](int tap, int ch, int buf){
            const int kd = tap/3, kw = tap - kd*3;
            const int tapoff = kd*ROWB + (kw*CIN + ch*32)*2;
            #pragma unroll
            for (int t=0;t<4;t++){
                int off = (tb[t] + tapoff) ^ swz[kw];
                pb[buf][t] = *reinterpret_cast<const short8*>(lds + off);
            }
        };

        #pragma unroll 1
        for (int ch=0; ch<NCH; ch++){
            __syncthreads();          // keep 4 waves lockstep -> weight L1 hits
            loadA(0, ch, 0); loadB(0, ch, 0);
            #pragma unroll
            for (int tap=0; tap<9; tap++){
                const int cb = tap&1, nb = (tap&1)^1;
                if (tap < 8){ loadA(tap+1, ch, nb); loadB(tap+1, ch, nb); }
                #pragma unroll
                for (int t=0;t<4;t++)
                    #pragma unroll
                    for (int ct=0; ct<4; ct++)
                        acc[ct][t] = __builtin_amdgcn_mfma_f32_16x16x32_bf16(pa[cb][ct], pb[cb][t], acc[ct][t], 0,0,0);
            }
        }

        // epilogue
        int ovox[4];
        #pragma unroll
        for (int t=0;t<4;t++){
            int o2r = r0 + w*2 + (t>>1);
            int o3  = (t&1)*16 + lj;
            ovox[t] = (KIND==0) ? ((o2r*ND2 + z)*ND3 + o3)
                                : ((z*ND2 + o2r)*ND3 + o3);
        }
        float mm[4];
        #pragma unroll
        for (int t=0;t<4;t++) mm[t] = mout[ovox[t]];
        __syncthreads();
        #pragma unroll
        for (int ct=0;ct<4;ct++){
            float s1[4] = {0.f,0.f,0.f,0.f};
            float s2[4] = {0.f,0.f,0.f,0.f};
            #pragma unroll
            for (int t=0;t<4;t++){
                float v[4];
                #pragma unroll
                for (int r=0;r<4;r++){
                    float xv = acc[ct][t][r]*mm[t];
                    xv = (xv >= 0.f) ? xv : 0.01f*xv;
                    v[r] = xv; s1[r] += xv; s2[r] += xv*xv;
                }
                unsigned lo = f2b(v[0]) | ((unsigned)f2b(v[1])<<16);
                unsigned hi = f2b(v[2]) | ((unsigned)f2b(v[3])<<16);
                *reinterpret_cast<uint2*>(outb + (size_t)ovox[t]*64 + ct*16 + g*4) = make_uint2(lo,hi);
            }
            #pragma unroll
            for (int r=0;r<4;r++){
                float a = s1[r], b = s2[r];
                a += __shfl_xor(a,1); b += __shfl_xor(b,1);
                a += __shfl_xor(a,2); b += __shfl_xor(b,2);
                a += __shfl_xor(a,4); b += __shfl_xor(b,4);
                a += __shfl_xor(a,8); b += __shfl_xor(b,8);
                if (lj == 0){
                    atomicAdd(&sst[ct*16 + g*4 + r], a);
                    atomicAdd(&sst[64 + ct*16 + g*4 + r], b);
                }
            }
        }
        __syncthreads();
        if (tid < 128) atomicAdd(&statsg[tid], sst[tid]);
        return;
    }

    // ---- KIND 2: pool ----
    if (KIND == 2){
        int tb2[2];
        #pragma unroll
        for (int t=0;t<2;t++){
            int o3 = t*16 + lj;
            tb2[t] = (o3*64 + g*8)*2;
        }
        f32x4 acc[4][2];
        #pragma unroll
        for (int a=0;a<4;a++)
            #pragma unroll
            for (int b=0;b<2;b++)
                #pragma unroll
                for (int q=0;q<4;q++) acc[a][b][q] = 0.f;

        short8 pa[2][4], pb[2][2];
        const int rrb = 2*w;

        #pragma unroll 1
        for (int kd=0; kd<3; kd++){
            __syncthreads();
            int d1 = 2*z - 1 + kd;
            bool pok = ((unsigned)d1 < (unsigned)ND1);
            #pragma unroll 1
            for (int rr=0; rr<9; rr++){
                int d2 = 2*r0 - 1 + rr;
                bool ok = pok && ((unsigned)d2 < (unsigned)ND2);
                int dst = rr*ROWB + (((sd3+1)*64 + k0)*2);
                dst ^= (((sd3+1)&7)<<4);
                uint4 v = make_uint4(0,0,0,0);
                if (ok){
                    int vox = (d1*ND2 + d2)*ND3 + sd3;
                    v = *reinterpret_cast<const uint4*>(in + (size_t)vox*64 + k0);
                }
                *reinterpret_cast<uint4*>(lds + dst) = v;
            }
            for (int i = tid; i < 9*2*8; i += 256){
                int rr = i / 16;
                int rem = i - rr*16;
                int slot = (rem >= 8) ? 33 : 0;
                int kc16 = rem & 7;
                int dst = rr*ROWB + slot*128 + kc16*16;
                dst ^= ((slot&7)<<4);
                *reinterpret_cast<uint4*>(lds + dst) = make_uint4(0,0,0,0);
            }
            __syncthreads();

            auto loadA2 = [&](int tap, int ch, int buf){
                const int kh = tap/3, kw = tap - kh*3;
                const int kc = ((kd*3+kh)*3+kw)*2 + ch;
                const unsigned short* wp = Wt + (size_t)kc*2048 + woff;
                #pragma unroll
                for (int ct=0;ct<4;ct++) pa[buf][ct] = *reinterpret_cast<const short8*>(wp + ct*512);
            };
            auto loadB2 = [&](int tap, int ch, int buf){
                const int kh = tap/3, kw = tap - kh*3;
                const int tapoff = (rrb + kh)*ROWB + (kw*64 + ch*32)*2;
                #pragma unroll
                for (int t=0;t<2;t++){
                    int off = (tb2[t] + tapoff) ^ swz[kw];
                    pb[buf][t] = *reinterpret_cast<const short8*>(lds + off);
                }
            };

            #pragma unroll 1
            for (int ch=0; ch<2; ch++){
                loadA2(0, ch, 0); loadB2(0, ch, 0);
                #pragma unroll
                for (int tap=0; tap<9; tap++){
                    const int cb = tap&1, nb = (tap&1)^1;
                    if (tap < 8){ loadA2(tap+1, ch, nb); loadB2(tap+1, ch, nb); }
                    #pragma unroll
                    for (int t=0;t<2;t++)
                        #pragma unroll
                        for (int ct=0; ct<4; ct++)
                            acc[ct][t] = __builtin_amdgcn_mfma_f32_16x16x32_bf16(pa[cb][ct], pb[cb][t], acc[ct][t], 0,0,0);
                }
            }
        }
        // epilogue
        #pragma unroll
        for (int t=0;t<2;t++){
            int o2 = r0 + w;
            int o3 = t*16 + lj;
            int ovox = (z*OD2 + o2)*OD3 + o3;
            float om = mout[ovox];
            #pragma unroll
            for (int ct=0;ct<4;ct++){
                #pragma unroll
                for (int r=0;r<4;r++){
                    int co = ct*16 + g*4 + r;
                    outf[(size_t)co*OSP + ovox] = acc[ct][t][r]*om;
                }
            }
        }
    }
}

// ---------------- launch ----------------
extern "C" void kernel_launch(void* const* d_in, const int* in_sizes, int n_in,
                              void* d_out, int out_size, void* d_ws, size_t ws_size,
                              hipStream_t stream)
{
    const float* x      = (const float*)d_in[0];
    const void*  mraw   = d_in[1];
    const float* W_A1   = (const float*)d_in[2];
    const float* W_A2   = (const float*)d_in[3];
    const float* W_B1   = (const float*)d_in[4];
    const float* W_B2   = (const float*)d_in[5];
    const float* W_pool = (const float*)d_in[6];
    const float* g_A1 = (const float*)d_in[7],  *b_A1 = (const float*)d_in[8];
    const float* g_A2 = (const float*)d_in[9],  *b_A2 = (const float*)d_in[10];
    const float* g_B1 = (const float*)d_in[11], *b_B1 = (const float*)d_in[12];
    const float* g_B2 = (const float*)d_in[13], *b_B2 = (const float*)d_in[14];

    char* p = (char*)d_ws;
    float* m     = (float*)p; p += (size_t)SP*4;
    float* omask = (float*)p; p += (size_t)OSP*4;
    float* stats = (float*)p; p += 4*128*4;
    float* scsh  = (float*)p; p += 4*128*4;
    float* nact  = (float*)p; p += 4;
    int*   flag  = (int*)p;   p += 4;
    p += 248;
    unsigned short* WtA1 = (unsigned short*)p; p += 288*64*2;
    unsigned short* WtA2 = (unsigned short*)p; p += 576*64*2;
    unsigned short* WtB1 = (unsigned short*)p; p += 288*64*2;
    unsigned short* WtB2 = (unsigned short*)p; p += 576*64*2;
    unsigned short* WtP  = (unsigned short*)p; p += 1728*64*2;
    unsigned short* X = (unsigned short*)p; p += (size_t)SP*32*2;
    unsigned short* P = (unsigned short*)p; p += (size_t)SP*64*2;
    unsigned short* Q = (unsigned short*)p; p += (size_t)SP*64*2;
    unsigned short* R = (unsigned short*)p; p += (size_t)SP*64*2;

    float* down = (float*)d_out;                 // [64][OSP]
    float* resf = down + (size_t)CO*OSP;         // [64][SP]

    hipMemsetAsync(stats, 0, 4*128*4*2 + 8, stream);
    k_detect<<<256, 256, 0, stream>>>((const unsigned char*)mraw, flag);
    k_mask<<<SP/256, 256, 0, stream>>>(mraw, flag, m, nact);
    k_outmask<<<OSP/256, 256, 0, stream>>>(m, omask);
    k_prep_x<<<SP/64, 256, 0, stream>>>(x, m, X);

    k_wprep<<<(64*288+255)/256, 256, 0, stream>>>(W_A1, WtA1, 32, 9);
    k_wprep<<<(64*576+255)/256, 256, 0, stream>>>(W_A2, WtA2, 64, 9);
    k_wprep<<<(64*288+255)/256, 256, 0, stream>>>(W_B1, WtB1, 32, 9);
    k_wprep<<<(64*576+255)/256, 256, 0, stream>>>(W_B2, WtB2, 64, 9);
    k_wprep<<<(64*1728+255)/256, 256, 0, stream>>>(W_pool, WtP, 64, 27);

    // A1: (3,1,3) on xs -> P, stats0
    mconv3<0,32,false><<<3200, 256, 0, stream>>>(X, WtA1, nullptr,nullptr,nullptr,nullptr,nullptr,
                                                 nullptr, m, P, nullptr, stats + 0);
    // A2: (1,3,3) on BN_A1(P) (affine in-prologue from stats0) -> R, stats1
    mconv3<1,64,true><<<3200, 256, 0, stream>>>(P, WtA2, stats+0, stats+64, nact, g_A1, b_A1,
                                                m, m, R, nullptr, stats + 128);
    // B1: (1,3,3) on xs -> Q, stats2
    mconv3<1,32,false><<<3200, 256, 0, stream>>>(X, WtB1, nullptr,nullptr,nullptr,nullptr,nullptr,
                                                 nullptr, m, Q, nullptr, stats + 256);
    // B2: (3,1,3) on BN_B1(Q) (affine in-prologue from stats2) -> P, stats3
    mconv3<0,64,true><<<3200, 256, 0, stream>>>(Q, WtB2, stats+256, stats+320, nact, g_B1, b_B1,
                                                m, m, P, nullptr, stats + 384);
    // finalize A2, B2 affines for resB
    k_finalize<<<1, 64, 0, stream>>>(stats + 128, stats + 192, nact, g_A2, b_A2, scsh + 0);
    k_finalize<<<1, 64, 0, stream>>>(stats + 384, stats + 448, nact, g_B2, b_B2, scsh + 128);
    // res_B combine -> Q (bf16 for pool) + resf (f32 output)
    k_resB<<<SP/64, 256, 0, stream>>>(R, P, scsh + 0, scsh + 128, m, Q, resf);
    // pool
    mconv3<2,64,false><<<1600, 256, 0, stream>>>(Q, WtP, nullptr,nullptr,nullptr,nullptr,nullptr,
                                                 nullptr, omask, nullptr, down, nullptr);
}

// Round 5
// 785.294 us; speedup vs baseline: 9.4314x; 1.1345x over previous
//
#include <hip/hip_runtime.h>

static constexpr int ND1=160, ND2=160, ND3=32;
static constexpr int SP  = ND1*ND2*ND3;        // 819200
static constexpr int CO  = 64;
static constexpr int OD1=80, OD2=80, OD3=32;
static constexpr int OSP = OD1*OD2*OD3;        // 204800
static constexpr int NSC = 64;                 // stat copies (contention spread)

typedef __attribute__((ext_vector_type(8))) short  short8;
typedef __attribute__((ext_vector_type(4))) float  f32x4;

__device__ __forceinline__ float b2f(unsigned u){ return __uint_as_float(u<<16); }
__device__ __forceinline__ unsigned short f2b(float f){
    unsigned u = __float_as_uint(f);
    u += 0x7fffu + ((u>>16)&1u);
    return (unsigned short)(u>>16);
}

// ---------------- mask dtype detection ----------------
__global__ void k_detect(const unsigned char* __restrict__ mb, int* __restrict__ flag)
{
    __shared__ int lf;
    if (threadIdx.x == 0) lf = 0;
    __syncthreads();
    int f = 0;
    for (int i = blockIdx.x*256 + threadIdx.x; i < SP; i += gridDim.x*256) {
        unsigned char b = mb[i];
        if (b > 1) f |= 4;
        if (b != 0 && (i & 3)) f |= 1;
    }
    if (f) atomicOr(&lf, f);
    __syncthreads();
    if (threadIdx.x == 0 && lf) atomicOr(flag, lf);
}

__global__ void k_mask(const void* __restrict__ mraw, const int* __restrict__ flag,
                       float* __restrict__ m, float* __restrict__ nactN)
{
    int i = blockIdx.x*256 + threadIdx.x;
    int f = *flag;
    float v;
    if (f & 4)      v = (reinterpret_cast<const float*>(mraw)[i] != 0.f) ? 1.f : 0.f;
    else if (f & 1) v = (reinterpret_cast<const unsigned char*>(mraw)[i] != 0) ? 1.f : 0.f;
    else            v = (reinterpret_cast<const int*>(mraw)[i] != 0) ? 1.f : 0.f;
    m[i] = v;
    float s = v;
    #pragma unroll
    for (int off = 32; off > 0; off >>= 1) s += __shfl_xor(s, off);
    __shared__ float wsum[4];
    if ((threadIdx.x & 63) == 0) wsum[threadIdx.x >> 6] = s;
    __syncthreads();
    if (threadIdx.x == 0) atomicAdd(&nactN[blockIdx.x & (NSC-1)], wsum[0]+wsum[1]+wsum[2]+wsum[3]);
}

__global__ void k_outmask(const float* __restrict__ m, float* __restrict__ om)
{
    int i = blockIdx.x*256 + threadIdx.x;   // < OSP
    int o3 = i & 31; int t = i >> 5; int o2 = t % OD2; int o1 = t / OD2;
    float s = 0.f;
    for (int kd = 0; kd < 3; kd++) { int d1 = 2*o1 - 1 + kd; if ((unsigned)d1 >= ND1) continue;
      for (int kh = 0; kh < 3; kh++) { int d2 = 2*o2 - 1 + kh; if ((unsigned)d2 >= ND2) continue;
        for (int kw = 0; kw < 3; kw++) { int d3 = o3 - 1 + kw; if ((unsigned)d3 >= ND3) continue;
          s += m[(d1*ND2 + d2)*ND3 + d3];
        } } }
    om[i] = (s > 0.f) ? 1.f : 0.f;
}

// ---------------- BN finalize: reduce NSC stat copies -> per-channel affine ----------------
__global__ void k_finalize2(const float* __restrict__ SN,    // [NSC][128]
                            const float* __restrict__ nactN, // [NSC]
                            const float* __restrict__ g, const float* __restrict__ b,
                            float* __restrict__ scsh)        // [128]
{
    int c = threadIdx.x;      // 64 threads = 1 wave
    float s1 = 0.f, s2 = 0.f;
    #pragma unroll 4
    for (int k = 0; k < NSC; k++){
        s1 += SN[k*128 + c];
        s2 += SN[k*128 + 64 + c];
    }
    float nn = nactN[c];
    #pragma unroll
    for (int off = 32; off > 0; off >>= 1) nn += __shfl_xor(nn, off);
    float mean = s1 / nn;
    float var  = s2 / nn - mean*mean;
    float inv  = rsqrtf(var + 1e-5f);
    float sc   = inv * g[c];
    scsh[c]      = sc;
    scsh[64 + c] = b[c] - mean*sc;
}

// ---------------- weight pre-pack: W[co][ci][tap] f32 -> Wt[kc][co][32] bf16 ----------------
__global__ void k_wprep(const float* __restrict__ W, unsigned short* __restrict__ Wt,
                        int CIN, int NT)
{
    int i = blockIdx.x*256 + threadIdx.x;
    int K = CIN*NT;
    if (i >= 64*K) return;
    int ksub = i & 31;
    int t = i >> 5;
    int co = t & 63;
    int kc = t >> 6;
    int nch = CIN >> 5;
    int tap = kc / nch;
    int ci  = (kc - tap*nch)*32 + ksub;
    Wt[i] = f2b(W[((size_t)co*CIN + ci)*NT + tap]);
}

// ---------------- x f32 [ci][sp] -> masked bf16 [sp][32] ----------------
__global__ void k_prep_x(const float* __restrict__ x, const float* __restrict__ m,
                         unsigned short* __restrict__ xt)
{
    __shared__ float t[64][33];
    int sp0 = blockIdx.x*64;
    int tid = threadIdx.x;
    int c = tid>>6, s = tid&63;
    float mm = m[sp0+s];
    #pragma unroll
    for (int r=0;r<8;r++){
        int ci = c + r*4;
        t[s][ci] = x[(size_t)ci*SP + sp0 + s]*mm;
    }
    __syncthreads();
    int sp = tid>>2, c0 = (tid&3)*8;
    unsigned short o[8];
    #pragma unroll
    for (int i=0;i<8;i++) o[i] = f2b(t[sp][c0+i]);
    uint4 pk;
    pk.x = o[0] | ((unsigned)o[1]<<16);
    pk.y = o[2] | ((unsigned)o[3]<<16);
    pk.z = o[4] | ((unsigned)o[5]<<16);
    pk.w = o[6] | ((unsigned)o[7]<<16);
    *reinterpret_cast<uint4*>(xt + (size_t)(sp0+sp)*32 + c0) = pk;
}

// ---------------- res_B combine ----------------
__global__ void k_resB(const unsigned short* __restrict__ hA, const unsigned short* __restrict__ hB,
                       const float* __restrict__ sA, const float* __restrict__ sB,
                       const float* __restrict__ m,
                       unsigned short* __restrict__ rbt, float* __restrict__ resf)
{
    __shared__ float t[64][65];
    __shared__ float ss[256];
    int tid = threadIdx.x;
    if (tid < 128){ ss[tid] = sA[tid]; ss[128+tid] = sB[tid]; }
    __syncthreads();
    int sp0 = blockIdx.x*64;
    int sp = tid>>2, c0 = (tid&3)*16;
    float mm = m[sp0+sp];
    const size_t base = (size_t)(sp0+sp)*64 + c0;
    uint4 a0 = *reinterpret_cast<const uint4*>(hA + base);
    uint4 a1 = *reinterpret_cast<const uint4*>(hA + base + 8);
    uint4 b0 = *reinterpret_cast<const uint4*>(hB + base);
    uint4 b1 = *reinterpret_cast<const uint4*>(hB + base + 8);
    unsigned ua[16] = {a0.x&0xffffu,a0.x>>16,a0.y&0xffffu,a0.y>>16,a0.z&0xffffu,a0.z>>16,a0.w&0xffffu,a0.w>>16,
                       a1.x&0xffffu,a1.x>>16,a1.y&0xffffu,a1.y>>16,a1.z&0xffffu,a1.z>>16,a1.w&0xffffu,a1.w>>16};
    unsigned ub[16] = {b0.x&0xffffu,b0.x>>16,b0.y&0xffffu,b0.y>>16,b0.z&0xffffu,b0.z>>16,b0.w&0xffffu,b0.w>>16,
                       b1.x&0xffffu,b1.x>>16,b1.y&0xffffu,b1.y>>16,b1.z&0xffffu,b1.z>>16,b1.w&0xffffu,b1.w>>16};
    unsigned short o[16];
    #pragma unroll
    for (int q=0;q<16;q++){
        int ci = c0+q;
        float v = (b2f(ua[q])*ss[ci] + ss[64+ci] + b2f(ub[q])*ss[128+ci] + ss[192+ci])*mm;
        t[sp][ci] = v;
        o[q] = f2b(v);
    }
    uint4 p0, p1;
    p0.x = o[0]|((unsigned)o[1]<<16);  p0.y = o[2]|((unsigned)o[3]<<16);
    p0.z = o[4]|((unsigned)o[5]<<16);  p0.w = o[6]|((unsigned)o[7]<<16);
    p1.x = o[8]|((unsigned)o[9]<<16);  p1.y = o[10]|((unsigned)o[11]<<16);
    p1.z = o[12]|((unsigned)o[13]<<16); p1.w = o[14]|((unsigned)o[15]<<16);
    *reinterpret_cast<uint4*>(rbt + base)     = p0;
    *reinterpret_cast<uint4*>(rbt + base + 8) = p1;
    __syncthreads();
    int ci = tid>>2, s0 = (tid&3)*16;
    #pragma unroll
    for (int kq=0;kq<4;kq++){
        float4 ov;
        ov.x = t[s0+4*kq+0][ci]; ov.y = t[s0+4*kq+1][ci];
        ov.z = t[s0+4*kq+2][ci]; ov.w = t[s0+4*kq+3][ci];
        *reinterpret_cast<float4*>(resf + (size_t)ci*SP + sp0 + s0 + 4*kq) = ov;
    }
}

// ---------------- MFMA conv, LDS-staged, pipelined, spread-atomic stats ----------------
// KIND 0: taps (3,1,3) rows=d1 ; KIND 1: taps (1,3,3) rows=d2 ; KIND 2: pool
template<int KIND, int CIN, bool HASAFF>
__launch_bounds__(256, (CIN==32 || KIND==2) ? 4 : 3)
__global__ void mconv4(const unsigned short* __restrict__ in,   // bf16 [vox][CIN]
                       const unsigned short* __restrict__ Wt,   // bf16 [kc][64co][32k]
                       const float* __restrict__ scsh,          // affine [128] (HASAFF)
                       const float* __restrict__ mstage,        // mask for staging (HASAFF)
                       const float* __restrict__ mout,          // mask at output voxel
                       unsigned short* __restrict__ outb,       // bf16 [vox][64] (KIND 0/1)
                       float* __restrict__ outf,                // f32 [co][OSP]  (KIND 2)
                       float* __restrict__ statsN)              // [NSC][128]
{
    constexpr int NCH  = CIN/32;
    constexpr int NR   = (KIND==2) ? 9 : 10;
    constexpr int ROWB = 34*CIN*2;
    constexpr int SWZ  = (CIN==64) ? 7 : 3;
    __shared__ __align__(16) char lds[NR*ROWB];
    __shared__ float sst[128];

    const int tid = threadIdx.x;
    const int w = tid>>6, l = tid&63, g = l>>4, lj = l&15;

    int gi = (blockIdx.x & 7)*(gridDim.x>>3) + (blockIdx.x>>3);
    int z, r0;
    if (KIND==2){ z = gi % OD1; r0 = (gi / OD1)*4; }
    else        { z = gi % 160; r0 = (gi / 160)*8; }

    if (KIND != 2) { if (tid < 128) sst[tid] = 0.f; }

    const int sd3 = tid>>3;              // 0..31
    const int k0  = (tid&7)*(CIN/8);     // 8 ch (CIN64) / 4 ch (CIN32)

    float sc[8], sh[8];
    if (HASAFF){
        #pragma unroll
        for (int j=0;j<8;j++){ sc[j]=scsh[k0+j]; sh[j]=scsh[64+k0+j]; }
    }

    // ---- stage (KIND 0/1) ----
    if (KIND != 2){
        #pragma unroll 1
        for (int rr=0; rr<NR; rr++){
            int rw = r0 - 1 + rr;
            bool ok = ((unsigned)rw < 160u);
            int dst = rr*ROWB + (((sd3+1)*CIN + k0)*2);
            dst ^= (((sd3+1)&SWZ)<<4);
            if (CIN==64){
                uint4 v = make_uint4(0,0,0,0);
                if (ok){
                    int vox = (KIND==0) ? ((rw*ND2 + z)*ND3 + sd3)
                                        : ((z*ND2 + rw)*ND3 + sd3);
                    v = *reinterpret_cast<const uint4*>(in + (size_t)vox*CIN + k0);
                    if (HASAFF){
                        float mm = mstage[vox];
                        unsigned us[8] = {v.x&0xffffu,v.x>>16,v.y&0xffffu,v.y>>16,
                                          v.z&0xffffu,v.z>>16,v.w&0xffffu,v.w>>16};
                        unsigned short o[8];
                        #pragma unroll
                        for (int j=0;j<8;j++) o[j] = f2b((b2f(us[j])*sc[j]+sh[j])*mm);
                        v.x = o[0]|((unsigned)o[1]<<16); v.y = o[2]|((unsigned)o[3]<<16);
                        v.z = o[4]|((unsigned)o[5]<<16); v.w = o[6]|((unsigned)o[7]<<16);
                    }
                }
                *reinterpret_cast<uint4*>(lds + dst) = v;
            } else {
                uint2 v = make_uint2(0,0);
                if (ok){
                    int vox = (KIND==0) ? ((rw*ND2 + z)*ND3 + sd3)
                                        : ((z*ND2 + rw)*ND3 + sd3);
                    v = *reinterpret_cast<const uint2*>(in + (size_t)vox*CIN + k0);
                }
                *reinterpret_cast<uint2*>(lds + dst) = v;
            }
        }
        for (int i = tid; i < NR*2*(CIN/8); i += 256){
            int per = CIN/8;
            int rr = i / (2*per);
            int rem = i - rr*2*per;
            int slot = (rem >= per) ? 33 : 0;
            int kc16 = (rem >= per) ? (rem - per) : rem;
            int dst = rr*ROWB + slot*CIN*2 + kc16*16;
            dst ^= ((slot&SWZ)<<4);
            *reinterpret_cast<uint4*>(lds + dst) = make_uint4(0,0,0,0);
        }
        __syncthreads();
    }

    int swz[3];
    #pragma unroll
    for (int kw=0;kw<3;kw++) swz[kw] = ((lj+kw)&SWZ)<<4;
    const int woff = lj*32 + g*8;

    if (KIND != 2){
        int tb[4];
        #pragma unroll
        for (int t=0;t<4;t++){
            int rowb = w*2 + (t>>1);
            int o3   = (t&1)*16 + lj;
            tb[t] = rowb*ROWB + ((o3*CIN + g*8)*2);
        }
        f32x4 acc[4][4];
        #pragma unroll
        for (int a=0;a<4;a++)
            #pragma unroll
            for (int b=0;b<4;b++)
                #pragma unroll
                for (int q=0;q<4;q++) acc[a][b][q] = 0.f;

        short8 pa[2][4], pb[2][4];
        auto loadA = [&](int tap, int ch, int buf){
            const unsigned short* wp = Wt + (size_t)(tap*NCH+ch)*2048 + woff;
            #pragma unroll
            for (int ct=0;ct<4;ct++) pa[buf][ct] = *reinterpret_cast<const short8*>(wp + ct*512);
        };
        auto loadB = [&](int tap, int ch, int buf){
            const int kd = tap/3, kw = tap - kd*3;
            const int tapoff = kd*ROWB + (kw*CIN + ch*32)*2;
            #pragma unroll
            for (int t=0;t<4;t++){
                int off = (tb[t] + tapoff) ^ swz[kw];
                pb[buf][t] = *reinterpret_cast<const short8*>(lds + off);
            }
        };

        #pragma unroll 1
        for (int ch=0; ch<NCH; ch++){
            __syncthreads();          // lockstep -> weight L1 hits
            loadA(0, ch, 0); loadB(0, ch, 0);
            #pragma unroll
            for (int tap=0; tap<9; tap++){
                const int cb = tap&1, nb = (tap&1)^1;
                if (tap < 8){ loadA(tap+1, ch, nb); loadB(tap+1, ch, nb); }
                #pragma unroll
                for (int t=0;t<4;t++)
                    #pragma unroll
                    for (int ct=0; ct<4; ct++)
                        acc[ct][t] = __builtin_amdgcn_mfma_f32_16x16x32_bf16(pa[cb][ct], pb[cb][t], acc[ct][t], 0,0,0);
            }
        }

        // epilogue
        int ovox[4];
        #pragma unroll
        for (int t=0;t<4;t++){
            int o2r = r0 + w*2 + (t>>1);
            int o3  = (t&1)*16 + lj;
            ovox[t] = (KIND==0) ? ((o2r*ND2 + z)*ND3 + o3)
                                : ((z*ND2 + o2r)*ND3 + o3);
        }
        float mm[4];
        #pragma unroll
        for (int t=0;t<4;t++) mm[t] = mout[ovox[t]];
        __syncthreads();
        #pragma unroll
        for (int ct=0;ct<4;ct++){
            float s1[4] = {0.f,0.f,0.f,0.f};
            float s2[4] = {0.f,0.f,0.f,0.f};
            #pragma unroll
            for (int t=0;t<4;t++){
                float v[4];
                #pragma unroll
                for (int r=0;r<4;r++){
                    float xv = acc[ct][t][r]*mm[t];
                    xv = (xv >= 0.f) ? xv : 0.01f*xv;
                    v[r] = xv; s1[r] += xv; s2[r] += xv*xv;
                }
                unsigned lo = f2b(v[0]) | ((unsigned)f2b(v[1])<<16);
                unsigned hi = f2b(v[2]) | ((unsigned)f2b(v[3])<<16);
                *reinterpret_cast<uint2*>(outb + (size_t)ovox[t]*64 + ct*16 + g*4) = make_uint2(lo,hi);
            }
            #pragma unroll
            for (int r=0;r<4;r++){
                float a = s1[r], b = s2[r];
                a += __shfl_xor(a,1); b += __shfl_xor(b,1);
                a += __shfl_xor(a,2); b += __shfl_xor(b,2);
                a += __shfl_xor(a,4); b += __shfl_xor(b,4);
                a += __shfl_xor(a,8); b += __shfl_xor(b,8);
                if (lj == 0){
                    atomicAdd(&sst[ct*16 + g*4 + r], a);
                    atomicAdd(&sst[64 + ct*16 + g*4 + r], b);
                }
            }
        }
        __syncthreads();
        if (tid < 128){
            float* sg = statsN + (size_t)(blockIdx.x & (NSC-1))*128;
            atomicAdd(&sg[tid], sst[tid]);
        }
        return;
    }

    // ---- KIND 2: pool ----
    if (KIND == 2){
        int tb2[2];
        #pragma unroll
        for (int t=0;t<2;t++){
            int o3 = t*16 + lj;
            tb2[t] = (o3*64 + g*8)*2;
        }
        f32x4 acc[4][2];
        #pragma unroll
        for (int a=0;a<4;a++)
            #pragma unroll
            for (int b=0;b<2;b++)
                #pragma unroll
                for (int q=0;q<4;q++) acc[a][b][q] = 0.f;

        short8 pa[2][4], pb[2][2];
        const int rrb = 2*w;

        #pragma unroll 1
        for (int kd=0; kd<3; kd++){
            __syncthreads();
            int d1 = 2*z - 1 + kd;
            bool pok = ((unsigned)d1 < (unsigned)ND1);
            #pragma unroll 1
            for (int rr=0; rr<9; rr++){
                int d2 = 2*r0 - 1 + rr;
                bool ok = pok && ((unsigned)d2 < (unsigned)ND2);
                int dst = rr*ROWB + (((sd3+1)*64 + k0)*2);
                dst ^= (((sd3+1)&7)<<4);
                uint4 v = make_uint4(0,0,0,0);
                if (ok){
                    int vox = (d1*ND2 + d2)*ND3 + sd3;
                    v = *reinterpret_cast<const uint4*>(in + (size_t)vox*64 + k0);
                }
                *reinterpret_cast<uint4*>(lds + dst) = v;
            }
            for (int i = tid; i < 9*2*8; i += 256){
                int rr = i / 16;
                int rem = i - rr*16;
                int slot = (rem >= 8) ? 33 : 0;
                int kc16 = rem & 7;
                int dst = rr*ROWB + slot*128 + kc16*16;
                dst ^= ((slot&7)<<4);
                *reinterpret_cast<uint4*>(lds + dst) = make_uint4(0,0,0,0);
            }
            __syncthreads();

            auto loadA2 = [&](int tap, int ch, int buf){
                const int kh = tap/3, kw = tap - kh*3;
                const int kc = ((kd*3+kh)*3+kw)*2 + ch;
                const unsigned short* wp = Wt + (size_t)kc*2048 + woff;
                #pragma unroll
                for (int ct=0;ct<4;ct++) pa[buf][ct] = *reinterpret_cast<const short8*>(wp + ct*512);
            };
            auto loadB2 = [&](int tap, int ch, int buf){
                const int kh = tap/3, kw = tap - kh*3;
                const int tapoff = (rrb + kh)*ROWB + (kw*64 + ch*32)*2;
                #pragma unroll
                for (int t=0;t<2;t++){
                    int off = (tb2[t] + tapoff) ^ swz[kw];
                    pb[buf][t] = *reinterpret_cast<const short8*>(lds + off);
                }
            };

            #pragma unroll 1
            for (int ch=0; ch<2; ch++){
                loadA2(0, ch, 0); loadB2(0, ch, 0);
                #pragma unroll
                for (int tap=0; tap<9; tap++){
                    const int cb = tap&1, nb = (tap&1)^1;
                    if (tap < 8){ loadA2(tap+1, ch, nb); loadB2(tap+1, ch, nb); }
                    #pragma unroll
                    for (int t=0;t<2;t++)
                        #pragma unroll
                        for (int ct=0; ct<4; ct++)
                            acc[ct][t] = __builtin_amdgcn_mfma_f32_16x16x32_bf16(pa[cb][ct], pb[cb][t], acc[ct][t], 0,0,0);
                }
            }
        }
        // epilogue
        #pragma unroll
        for (int t=0;t<2;t++){
            int o2 = r0 + w;
            int o3 = t*16 + lj;
            int ovox = (z*OD2 + o2)*OD3 + o3;
            float om = mout[ovox];
            #pragma unroll
            for (int ct=0;ct<4;ct++){
                #pragma unroll
                for (int r=0;r<4;r++){
                    int co = ct*16 + g*4 + r;
                    outf[(size_t)co*OSP + ovox] = acc[ct][t][r]*om;
                }
            }
        }
    }
}

// ---------------- launch ----------------
extern "C" void kernel_launch(void* const* d_in, const int* in_sizes, int n_in,
                              void* d_out, int out_size, void* d_ws, size_t ws_size,
                              hipStream_t stream)
{
    const float* x      = (const float*)d_in[0];
    const void*  mraw   = d_in[1];
    const float* W_A1   = (const float*)d_in[2];
    const float* W_A2   = (const float*)d_in[3];
    const float* W_B1   = (const float*)d_in[4];
    const float* W_B2   = (const float*)d_in[5];
    const float* W_pool = (const float*)d_in[6];
    const float* g_A1 = (const float*)d_in[7],  *b_A1 = (const float*)d_in[8];
    const float* g_A2 = (const float*)d_in[9],  *b_A2 = (const float*)d_in[10];
    const float* g_B1 = (const float*)d_in[11], *b_B1 = (const float*)d_in[12];
    const float* g_B2 = (const float*)d_in[13], *b_B2 = (const float*)d_in[14];

    char* p = (char*)d_ws;
    float* m     = (float*)p; p += (size_t)SP*4;
    float* omask = (float*)p; p += (size_t)OSP*4;
    float* statsN= (float*)p; p += 4*NSC*128*4;      // 4 stages x [NSC][128]
    float* scsh  = (float*)p; p += 4*128*4;
    float* nactN = (float*)p; p += NSC*4;
    int*   flag  = (int*)p;   p += 4;
    p += 252;
    unsigned short* WtA1 = (unsigned short*)p; p += 288*64*2;
    unsigned short* WtA2 = (unsigned short*)p; p += 576*64*2;
    unsigned short* WtB1 = (unsigned short*)p; p += 288*64*2;
    unsigned short* WtB2 = (unsigned short*)p; p += 576*64*2;
    unsigned short* WtP  = (unsigned short*)p; p += 1728*64*2;
    unsigned short* X = (unsigned short*)p; p += (size_t)SP*32*2;
    unsigned short* P = (unsigned short*)p; p += (size_t)SP*64*2;
    unsigned short* Q = (unsigned short*)p; p += (size_t)SP*64*2;
    unsigned short* R = (unsigned short*)p; p += (size_t)SP*64*2;

    float* down = (float*)d_out;                 // [64][OSP]
    float* resf = down + (size_t)CO*OSP;         // [64][SP]

    // zero statsN + scsh + nactN + flag in one shot
    hipMemsetAsync(statsN, 0, (4*NSC*128 + 4*128 + NSC)*4 + 4, stream);
    k_detect<<<256, 256, 0, stream>>>((const unsigned char*)mraw, flag);
    k_mask<<<SP/256, 256, 0, stream>>>(mraw, flag, m, nactN);
    k_outmask<<<OSP/256, 256, 0, stream>>>(m, omask);
    k_prep_x<<<SP/64, 256, 0, stream>>>(x, m, X);

    k_wprep<<<(64*288+255)/256, 256, 0, stream>>>(W_A1, WtA1, 32, 9);
    k_wprep<<<(64*576+255)/256, 256, 0, stream>>>(W_A2, WtA2, 64, 9);
    k_wprep<<<(64*288+255)/256, 256, 0, stream>>>(W_B1, WtB1, 32, 9);
    k_wprep<<<(64*576+255)/256, 256, 0, stream>>>(W_B2, WtB2, 64, 9);
    k_wprep<<<(64*1728+255)/256, 256, 0, stream>>>(W_pool, WtP, 64, 27);

    float* SA1 = statsN + 0*NSC*128;
    float* SA2 = statsN + 1*NSC*128;
    float* SB1 = statsN + 2*NSC*128;
    float* SB2 = statsN + 3*NSC*128;

    // A1: (3,1,3) on xs -> P, SA1
    mconv4<0,32,false><<<3200, 256, 0, stream>>>(X, WtA1, nullptr, nullptr, m, P, nullptr, SA1);
    k_finalize2<<<1, 64, 0, stream>>>(SA1, nactN, g_A1, b_A1, scsh + 0);
    // A2: (1,3,3) on BN_A1(P) -> R, SA2
    mconv4<1,64,true><<<3200, 256, 0, stream>>>(P, WtA2, scsh + 0, m, m, R, nullptr, SA2);
    k_finalize2<<<1, 64, 0, stream>>>(SA2, nactN, g_A2, b_A2, scsh + 128);
    // B1: (1,3,3) on xs -> Q, SB1
    mconv4<1,32,false><<<3200, 256, 0, stream>>>(X, WtB1, nullptr, nullptr, m, Q, nullptr, SB1);
    k_finalize2<<<1, 64, 0, stream>>>(SB1, nactN, g_B1, b_B1, scsh + 256);
    // B2: (3,1,3) on BN_B1(Q) -> P, SB2
    mconv4<0,64,true><<<3200, 256, 0, stream>>>(Q, WtB2, scsh + 256, m, m, P, nullptr, SB2);
    k_finalize2<<<1, 64, 0, stream>>>(SB2, nactN, g_B2, b_B2, scsh + 384);
    // res_B combine -> Q (bf16 for pool) + resf (f32 output)
    k_resB<<<SP/64, 256, 0, stream>>>(R, P, scsh + 128, scsh + 384, m, Q, resf);
    // pool
    mconv4<2,64,false><<<1600, 256, 0, stream>>>(Q, WtP, nullptr, nullptr, omask, nullptr, down, nullptr);
}

// Round 6
// 757.535 us; speedup vs baseline: 9.7770x; 1.0366x over previous
//
#include <hip/hip_runtime.h>

static constexpr int ND1=160, ND2=160, ND3=32;
static constexpr int SP  = ND1*ND2*ND3;        // 819200
static constexpr int CO  = 64;
static constexpr int OD1=80, OD2=80, OD3=32;
static constexpr int OSP = OD1*OD2*OD3;        // 204800
static constexpr int NSC = 64;                 // stat copies (contention spread)

typedef __attribute__((ext_vector_type(8))) short  short8;
typedef __attribute__((ext_vector_type(4))) float  f32x4;

__device__ __forceinline__ float b2f(unsigned u){ return __uint_as_float(u<<16); }
__device__ __forceinline__ unsigned short f2b(float f){
    unsigned u = __float_as_uint(f);
    u += 0x7fffu + ((u>>16)&1u);
    return (unsigned short)(u>>16);
}

// ---------------- mask dtype detection ----------------
__global__ void k_detect(const unsigned char* __restrict__ mb, int* __restrict__ flag)
{
    __shared__ int lf;
    if (threadIdx.x == 0) lf = 0;
    __syncthreads();
    int f = 0;
    for (int i = blockIdx.x*256 + threadIdx.x; i < SP; i += gridDim.x*256) {
        unsigned char b = mb[i];
        if (b > 1) f |= 4;
        if (b != 0 && (i & 3)) f |= 1;
    }
    if (f) atomicOr(&lf, f);
    __syncthreads();
    if (threadIdx.x == 0 && lf) atomicOr(flag, lf);
}

__global__ void k_mask(const void* __restrict__ mraw, const int* __restrict__ flag,
                       float* __restrict__ m, float* __restrict__ nactN)
{
    int i = blockIdx.x*256 + threadIdx.x;
    int f = *flag;
    float v;
    if (f & 4)      v = (reinterpret_cast<const float*>(mraw)[i] != 0.f) ? 1.f : 0.f;
    else if (f & 1) v = (reinterpret_cast<const unsigned char*>(mraw)[i] != 0) ? 1.f : 0.f;
    else            v = (reinterpret_cast<const int*>(mraw)[i] != 0) ? 1.f : 0.f;
    m[i] = v;
    float s = v;
    #pragma unroll
    for (int off = 32; off > 0; off >>= 1) s += __shfl_xor(s, off);
    __shared__ float wsum[4];
    if ((threadIdx.x & 63) == 0) wsum[threadIdx.x >> 6] = s;
    __syncthreads();
    if (threadIdx.x == 0) atomicAdd(&nactN[blockIdx.x & (NSC-1)], wsum[0]+wsum[1]+wsum[2]+wsum[3]);
}

__global__ void k_outmask(const float* __restrict__ m, float* __restrict__ om)
{
    int i = blockIdx.x*256 + threadIdx.x;   // < OSP
    int o3 = i & 31; int t = i >> 5; int o2 = t % OD2; int o1 = t / OD2;
    float s = 0.f;
    for (int kd = 0; kd < 3; kd++) { int d1 = 2*o1 - 1 + kd; if ((unsigned)d1 >= ND1) continue;
      for (int kh = 0; kh < 3; kh++) { int d2 = 2*o2 - 1 + kh; if ((unsigned)d2 >= ND2) continue;
        for (int kw = 0; kw < 3; kw++) { int d3 = o3 - 1 + kw; if ((unsigned)d3 >= ND3) continue;
          s += m[(d1*ND2 + d2)*ND3 + d3];
        } } }
    om[i] = (s > 0.f) ? 1.f : 0.f;
}

// ---------------- BN finalize: reduce NSC stat copies -> per-channel affine (2 stages/launch) ----------------
__global__ void k_finalize2(const float* __restrict__ SN0, const float* __restrict__ g0,
                            const float* __restrict__ b0, float* __restrict__ o0,
                            const float* __restrict__ SN1, const float* __restrict__ g1,
                            const float* __restrict__ b1, float* __restrict__ o1,
                            const float* __restrict__ nactN)
{
    const float* SN = blockIdx.x ? SN1 : SN0;
    const float* g  = blockIdx.x ? g1  : g0;
    const float* b  = blockIdx.x ? b1  : b0;
    float*       o  = blockIdx.x ? o1  : o0;
    int c = threadIdx.x;      // 64 threads = 1 wave
    float s1 = 0.f, s2 = 0.f;
    #pragma unroll 4
    for (int k = 0; k < NSC; k++){
        s1 += SN[k*128 + c];
        s2 += SN[k*128 + 64 + c];
    }
    float nn = nactN[c];
    #pragma unroll
    for (int off = 32; off > 0; off >>= 1) nn += __shfl_xor(nn, off);
    float mean = s1 / nn;
    float var  = s2 / nn - mean*mean;
    float inv  = rsqrtf(var + 1e-5f);
    float sc   = inv * g[c];
    o[c]      = sc;
    o[64 + c] = b[c] - mean*sc;
}

// ---------------- weight pre-pack: W[co][ci][tap] f32 -> Wt[kc][co][32] bf16 ----------------
__global__ void k_wprep(const float* __restrict__ W, unsigned short* __restrict__ Wt,
                        int CIN, int NT)
{
    int i = blockIdx.x*256 + threadIdx.x;
    int K = CIN*NT;
    if (i >= 64*K) return;
    int ksub = i & 31;
    int t = i >> 5;
    int co = t & 63;
    int kc = t >> 6;
    int nch = CIN >> 5;
    int tap = kc / nch;
    int ci  = (kc - tap*nch)*32 + ksub;
    Wt[i] = f2b(W[((size_t)co*CIN + ci)*NT + tap]);
}

// ---------------- x f32 [ci][sp] -> masked bf16 [sp][32] ----------------
__global__ void k_prep_x(const float* __restrict__ x, const float* __restrict__ m,
                         unsigned short* __restrict__ xt)
{
    __shared__ float t[64][33];
    int sp0 = blockIdx.x*64;
    int tid = threadIdx.x;
    int c = tid>>6, s = tid&63;
    float mm = m[sp0+s];
    #pragma unroll
    for (int r=0;r<8;r++){
        int ci = c + r*4;
        t[s][ci] = x[(size_t)ci*SP + sp0 + s]*mm;
    }
    __syncthreads();
    int sp = tid>>2, c0 = (tid&3)*8;
    unsigned short o[8];
    #pragma unroll
    for (int i=0;i<8;i++) o[i] = f2b(t[sp][c0+i]);
    uint4 pk;
    pk.x = o[0] | ((unsigned)o[1]<<16);
    pk.y = o[2] | ((unsigned)o[3]<<16);
    pk.z = o[4] | ((unsigned)o[5]<<16);
    pk.w = o[6] | ((unsigned)o[7]<<16);
    *reinterpret_cast<uint4*>(xt + (size_t)(sp0+sp)*32 + c0) = pk;
}

// ---------------- res_B combine ----------------
__global__ void k_resB(const unsigned short* __restrict__ hA, const unsigned short* __restrict__ hB,
                       const float* __restrict__ sA, const float* __restrict__ sB,
                       const float* __restrict__ m,
                       unsigned short* __restrict__ rbt, float* __restrict__ resf)
{
    __shared__ float t[64][65];
    __shared__ float ss[256];
    int tid = threadIdx.x;
    if (tid < 128){ ss[tid] = sA[tid]; ss[128+tid] = sB[tid]; }
    __syncthreads();
    int sp0 = blockIdx.x*64;
    int sp = tid>>2, c0 = (tid&3)*16;
    float mm = m[sp0+sp];
    const size_t base = (size_t)(sp0+sp)*64 + c0;
    uint4 a0 = *reinterpret_cast<const uint4*>(hA + base);
    uint4 a1 = *reinterpret_cast<const uint4*>(hA + base + 8);
    uint4 b0 = *reinterpret_cast<const uint4*>(hB + base);
    uint4 b1 = *reinterpret_cast<const uint4*>(hB + base + 8);
    unsigned ua[16] = {a0.x&0xffffu,a0.x>>16,a0.y&0xffffu,a0.y>>16,a0.z&0xffffu,a0.z>>16,a0.w&0xffffu,a0.w>>16,
                       a1.x&0xffffu,a1.x>>16,a1.y&0xffffu,a1.y>>16,a1.z&0xffffu,a1.z>>16,a1.w&0xffffu,a1.w>>16};
    unsigned ub[16] = {b0.x&0xffffu,b0.x>>16,b0.y&0xffffu,b0.y>>16,b0.z&0xffffu,b0.z>>16,b0.w&0xffffu,b0.w>>16,
                       b1.x&0xffffu,b1.x>>16,b1.y&0xffffu,b1.y>>16,b1.z&0xffffu,b1.z>>16,b1.w&0xffffu,b1.w>>16};
    unsigned short o[16];
    #pragma unroll
    for (int q=0;q<16;q++){
        int ci = c0+q;
        float v = (b2f(ua[q])*ss[ci] + ss[64+ci] + b2f(ub[q])*ss[128+ci] + ss[192+ci])*mm;
        t[sp][ci] = v;
        o[q] = f2b(v);
    }
    uint4 p0, p1;
    p0.x = o[0]|((unsigned)o[1]<<16);  p0.y = o[2]|((unsigned)o[3]<<16);
    p0.z = o[4]|((unsigned)o[5]<<16);  p0.w = o[6]|((unsigned)o[7]<<16);
    p1.x = o[8]|((unsigned)o[9]<<16);  p1.y = o[10]|((unsigned)o[11]<<16);
    p1.z = o[12]|((unsigned)o[13]<<16); p1.w = o[14]|((unsigned)o[15]<<16);
    *reinterpret_cast<uint4*>(rbt + base)     = p0;
    *reinterpret_cast<uint4*>(rbt + base + 8) = p1;
    __syncthreads();
    int ci = tid>>2, s0 = (tid&3)*16;
    #pragma unroll
    for (int kq=0;kq<4;kq++){
        float4 ov;
        ov.x = t[s0+4*kq+0][ci]; ov.y = t[s0+4*kq+1][ci];
        ov.z = t[s0+4*kq+2][ci]; ov.w = t[s0+4*kq+3][ci];
        *reinterpret_cast<float4*>(resf + (size_t)ci*SP + sp0 + s0 + 4*kq) = ov;
    }
}

// ---------------- MFMA conv, LDS-staged, batched staging loads ----------------
// KIND 0: taps (3,1,3) rows=d1 ; KIND 1: taps (1,3,3) rows=d2 ; KIND 2: pool
template<int KIND, int CIN, bool HASAFF>
__launch_bounds__(256, (CIN==32 || KIND==2) ? 4 : 3)
__global__ void mconv5(const unsigned short* __restrict__ in,   // bf16 [vox][CIN]
                       const unsigned short* __restrict__ Wt,   // bf16 [kc][64co][32k]
                       const float* __restrict__ scsh,          // affine [128] (HASAFF)
                       const float* __restrict__ mstage,        // mask for staging (HASAFF)
                       const float* __restrict__ mout,          // mask at output voxel
                       unsigned short* __restrict__ outb,       // bf16 [vox][64] (KIND 0/1)
                       float* __restrict__ outf,                // f32 [co][OSP]  (KIND 2)
                       float* __restrict__ statsN)              // [NSC][128]
{
    constexpr int NCH  = CIN/32;
    constexpr int NR   = (KIND==2) ? 9 : 10;
    constexpr int ROWB = 34*CIN*2;
    constexpr int SWZ  = (CIN==64) ? 7 : 3;
    __shared__ __align__(16) char lds[NR*ROWB];
    __shared__ float sst[128];

    const int tid = threadIdx.x;
    const int w = tid>>6, l = tid&63, g = l>>4, lj = l&15;

    int gi = (blockIdx.x & 7)*(gridDim.x>>3) + (blockIdx.x>>3);
    int z, r0;
    if (KIND==2){ z = gi % OD1; r0 = (gi / OD1)*4; }
    else        { z = gi % 160; r0 = (gi / 160)*8; }

    if (KIND != 2) { if (tid < 128) sst[tid] = 0.f; }

    const int sd3 = tid>>3;              // 0..31
    const int k0  = (tid&7)*(CIN/8);     // 8 ch (CIN64) / 4 ch (CIN32)

    float sc[8], sh[8];
    if (HASAFF){
        #pragma unroll
        for (int j=0;j<8;j++){ sc[j]=scsh[k0+j]; sh[j]=scsh[64+k0+j]; }
    }

    // border zero slots (0 and 33) — constant, write once
    for (int i = tid; i < NR*2*(CIN/8); i += 256){
        int per = CIN/8;
        int rr = i / (2*per);
        int rem = i - rr*2*per;
        int slot = (rem >= per) ? 33 : 0;
        int kc16 = (rem >= per) ? (rem - per) : rem;
        int dst = rr*ROWB + slot*CIN*2 + kc16*16;
        dst ^= ((slot&SWZ)<<4);
        *reinterpret_cast<uint4*>(lds + dst) = make_uint4(0,0,0,0);
    }

    // ---- stage (KIND 0/1): batched loads, one wait, then writes ----
    if (KIND != 2){
        if (CIN==64){
            uint4 v[NR]; float mmr[NR];
            #pragma unroll
            for (int rr=0; rr<NR; rr++){
                int rw = r0 - 1 + rr;
                v[rr] = make_uint4(0,0,0,0); mmr[rr] = 0.f;
                if ((unsigned)rw < 160u){
                    int vox = (KIND==0) ? ((rw*ND2 + z)*ND3 + sd3)
                                        : ((z*ND2 + rw)*ND3 + sd3);
                    v[rr] = *reinterpret_cast<const uint4*>(in + (size_t)vox*CIN + k0);
                    if (HASAFF) mmr[rr] = mstage[vox];
                }
            }
            #pragma unroll
            for (int rr=0; rr<NR; rr++){
                uint4 vv = v[rr];
                if (HASAFF){
                    float mm = mmr[rr];
                    unsigned us[8] = {vv.x&0xffffu,vv.x>>16,vv.y&0xffffu,vv.y>>16,
                                      vv.z&0xffffu,vv.z>>16,vv.w&0xffffu,vv.w>>16};
                    unsigned short o[8];
                    #pragma unroll
                    for (int j=0;j<8;j++) o[j] = f2b((b2f(us[j])*sc[j]+sh[j])*mm);
                    vv.x = o[0]|((unsigned)o[1]<<16); vv.y = o[2]|((unsigned)o[3]<<16);
                    vv.z = o[4]|((unsigned)o[5]<<16); vv.w = o[6]|((unsigned)o[7]<<16);
                }
                int dst = (rr*ROWB + (((sd3+1)*CIN + k0)*2)) ^ (((sd3+1)&SWZ)<<4);
                *reinterpret_cast<uint4*>(lds + dst) = vv;
            }
        } else {
            uint2 v[NR];
            #pragma unroll
            for (int rr=0; rr<NR; rr++){
                int rw = r0 - 1 + rr;
                v[rr] = make_uint2(0,0);
                if ((unsigned)rw < 160u){
                    int vox = (KIND==0) ? ((rw*ND2 + z)*ND3 + sd3)
                                        : ((z*ND2 + rw)*ND3 + sd3);
                    v[rr] = *reinterpret_cast<const uint2*>(in + (size_t)vox*CIN + k0);
                }
            }
            #pragma unroll
            for (int rr=0; rr<NR; rr++){
                int dst = (rr*ROWB + (((sd3+1)*CIN + k0)*2)) ^ (((sd3+1)&SWZ)<<4);
                *reinterpret_cast<uint2*>(lds + dst) = v[rr];
            }
        }
        __syncthreads();
    }

    int swz[3];
    #pragma unroll
    for (int kw=0;kw<3;kw++) swz[kw] = ((lj+kw)&SWZ)<<4;
    const int woff = lj*32 + g*8;

    if (KIND != 2){
        int tb[4], ovox[4];
        float mm[4];
        #pragma unroll
        for (int t=0;t<4;t++){
            int rowb = w*2 + (t>>1);
            int o3   = (t&1)*16 + lj;
            tb[t] = rowb*ROWB + ((o3*CIN + g*8)*2);
            int o2r = r0 + w*2 + (t>>1);
            ovox[t] = (KIND==0) ? ((o2r*ND2 + z)*ND3 + o3)
                                : ((z*ND2 + o2r)*ND3 + o3);
            mm[t] = mout[ovox[t]];     // hoisted: latency hides under compute
        }
        f32x4 acc[4][4];
        #pragma unroll
        for (int a=0;a<4;a++)
            #pragma unroll
            for (int b=0;b<4;b++)
                #pragma unroll
                for (int q=0;q<4;q++) acc[a][b][q] = 0.f;

        short8 pa[2][4], pb[2][4];
        auto loadA = [&](int tap, int ch, int buf){
            const unsigned short* wp = Wt + (size_t)(tap*NCH+ch)*2048 + woff;
            #pragma unroll
            for (int ct=0;ct<4;ct++) pa[buf][ct] = *reinterpret_cast<const short8*>(wp + ct*512);
        };
        auto loadB = [&](int tap, int ch, int buf){
            const int kd = tap/3, kw = tap - kd*3;
            const int tapoff = kd*ROWB + (kw*CIN + ch*32)*2;
            #pragma unroll
            for (int t=0;t<4;t++){
                int off = (tb[t] + tapoff) ^ swz[kw];
                pb[buf][t] = *reinterpret_cast<const short8*>(lds + off);
            }
        };

        #pragma unroll 1
        for (int ch=0; ch<NCH; ch++){
            __syncthreads();          // lockstep -> weight L1 hits
            loadA(0, ch, 0); loadB(0, ch, 0);
            #pragma unroll
            for (int tap=0; tap<9; tap++){
                const int cb = tap&1, nb = (tap&1)^1;
                if (tap < 8){ loadA(tap+1, ch, nb); loadB(tap+1, ch, nb); }
                #pragma unroll
                for (int t=0;t<4;t++)
                    #pragma unroll
                    for (int ct=0; ct<4; ct++)
                        acc[ct][t] = __builtin_amdgcn_mfma_f32_16x16x32_bf16(pa[cb][ct], pb[cb][t], acc[ct][t], 0,0,0);
            }
        }

        // epilogue
        __syncthreads();
        #pragma unroll
        for (int ct=0;ct<4;ct++){
            float s1[4] = {0.f,0.f,0.f,0.f};
            float s2[4] = {0.f,0.f,0.f,0.f};
            #pragma unroll
            for (int t=0;t<4;t++){
                float v[4];
                #pragma unroll
                for (int r=0;r<4;r++){
                    float xv = acc[ct][t][r]*mm[t];
                    xv = (xv >= 0.f) ? xv : 0.01f*xv;
                    v[r] = xv; s1[r] += xv; s2[r] += xv*xv;
                }
                unsigned lo = f2b(v[0]) | ((unsigned)f2b(v[1])<<16);
                unsigned hi = f2b(v[2]) | ((unsigned)f2b(v[3])<<16);
                *reinterpret_cast<uint2*>(outb + (size_t)ovox[t]*64 + ct*16 + g*4) = make_uint2(lo,hi);
            }
            #pragma unroll
            for (int r=0;r<4;r++){
                float a = s1[r], b = s2[r];
                a += __shfl_xor(a,1); b += __shfl_xor(b,1);
                a += __shfl_xor(a,2); b += __shfl_xor(b,2);
                a += __shfl_xor(a,4); b += __shfl_xor(b,4);
                a += __shfl_xor(a,8); b += __shfl_xor(b,8);
                if (lj == 0){
                    atomicAdd(&sst[ct*16 + g*4 + r], a);
                    atomicAdd(&sst[64 + ct*16 + g*4 + r], b);
                }
            }
        }
        __syncthreads();
        if (tid < 128){
            float* sg = statsN + (size_t)(blockIdx.x & (NSC-1))*128;
            atomicAdd(&sg[tid], sst[tid]);
        }
        return;
    }

    // ---- KIND 2: pool ----
    if (KIND == 2){
        int tb2[2], ovx[2];
        float om[2];
        #pragma unroll
        for (int t=0;t<2;t++){
            int o3 = t*16 + lj;
            tb2[t] = (o3*64 + g*8)*2;
            ovx[t] = (z*OD2 + (r0 + w))*OD3 + o3;
            om[t]  = mout[ovx[t]];
        }
        f32x4 acc[4][2];
        #pragma unroll
        for (int a=0;a<4;a++)
            #pragma unroll
            for (int b=0;b<2;b++)
                #pragma unroll
                for (int q=0;q<4;q++) acc[a][b][q] = 0.f;

        short8 pa[2][4], pb[2][2];
        const int rrb = 2*w;

        uint4 rv[9];
        auto issue_plane = [&](int kd, uint4 (&dst)[9]){
            int d1 = 2*z - 1 + kd;
            bool pok = ((unsigned)d1 < (unsigned)ND1);
            #pragma unroll
            for (int rr=0; rr<9; rr++){
                int d2 = 2*r0 - 1 + rr;
                dst[rr] = make_uint4(0,0,0,0);
                if (pok && ((unsigned)d2 < (unsigned)ND2)){
                    int vox = (d1*ND2 + d2)*ND3 + sd3;
                    dst[rr] = *reinterpret_cast<const uint4*>(in + (size_t)vox*64 + k0);
                }
            }
        };

        #pragma unroll 1
        for (int kd=0; kd<3; kd++){
            issue_plane(kd, rv);          // loads in flight across the barrier
            __syncthreads();              // prev plane's compute done
            #pragma unroll
            for (int rr=0; rr<9; rr++){
                int dst = (rr*ROWB + (((sd3+1)*64 + k0)*2)) ^ (((sd3+1)&7)<<4);
                *reinterpret_cast<uint4*>(lds + dst) = rv[rr];
            }
            __syncthreads();

            auto loadA2 = [&](int tap, int ch, int buf){
                const int kh = tap/3, kw = tap - kh*3;
                const int kc = ((kd*3+kh)*3+kw)*2 + ch;
                const unsigned short* wp = Wt + (size_t)kc*2048 + woff;
                #pragma unroll
                for (int ct=0;ct<4;ct++) pa[buf][ct] = *reinterpret_cast<const short8*>(wp + ct*512);
            };
            auto loadB2 = [&](int tap, int ch, int buf){
                const int kh = tap/3, kw = tap - kh*3;
                const int tapoff = (rrb + kh)*ROWB + (kw*64 + ch*32)*2;
                #pragma unroll
                for (int t=0;t<2;t++){
                    int off = (tb2[t] + tapoff) ^ swz[kw];
                    pb[buf][t] = *reinterpret_cast<const short8*>(lds + off);
                }
            };

            #pragma unroll 1
            for (int ch=0; ch<2; ch++){
                loadA2(0, ch, 0); loadB2(0, ch, 0);
                #pragma unroll
                for (int tap=0; tap<9; tap++){
                    const int cb = tap&1, nb = (tap&1)^1;
                    if (tap < 8){ loadA2(tap+1, ch, nb); loadB2(tap+1, ch, nb); }
                    #pragma unroll
                    for (int t=0;t<2;t++)
                        #pragma unroll
                        for (int ct=0; ct<4; ct++)
                            acc[ct][t] = __builtin_amdgcn_mfma_f32_16x16x32_bf16(pa[cb][ct], pb[cb][t], acc[ct][t], 0,0,0);
                }
            }
        }
        // epilogue
        #pragma unroll
        for (int t=0;t<2;t++){
            #pragma unroll
            for (int ct=0;ct<4;ct++){
                #pragma unroll
                for (int r=0;r<4;r++){
                    int co = ct*16 + g*4 + r;
                    outf[(size_t)co*OSP + ovx[t]] = acc[ct][t][r]*om[t];
                }
            }
        }
    }
}

// ---------------- launch ----------------
extern "C" void kernel_launch(void* const* d_in, const int* in_sizes, int n_in,
                              void* d_out, int out_size, void* d_ws, size_t ws_size,
                              hipStream_t stream)
{
    const float* x      = (const float*)d_in[0];
    const void*  mraw   = d_in[1];
    const float* W_A1   = (const float*)d_in[2];
    const float* W_A2   = (const float*)d_in[3];
    const float* W_B1   = (const float*)d_in[4];
    const float* W_B2   = (const float*)d_in[5];
    const float* W_pool = (const float*)d_in[6];
    const float* g_A1 = (const float*)d_in[7],  *b_A1 = (const float*)d_in[8];
    const float* g_A2 = (const float*)d_in[9],  *b_A2 = (const float*)d_in[10];
    const float* g_B1 = (const float*)d_in[11], *b_B1 = (const float*)d_in[12];
    const float* g_B2 = (const float*)d_in[13], *b_B2 = (const float*)d_in[14];

    char* p = (char*)d_ws;
    float* m     = (float*)p; p += (size_t)SP*4;
    float* omask = (float*)p; p += (size_t)OSP*4;
    float* statsN= (float*)p; p += 4*NSC*128*4;      // 4 stages x [NSC][128]
    float* scsh  = (float*)p; p += 4*128*4;
    float* nactN = (float*)p; p += NSC*4;
    int*   flag  = (int*)p;   p += 4;
    p += 252;
    unsigned short* WtA1 = (unsigned short*)p; p += 288*64*2;
    unsigned short* WtA2 = (unsigned short*)p; p += 576*64*2;
    unsigned short* WtB1 = (unsigned short*)p; p += 288*64*2;
    unsigned short* WtB2 = (unsigned short*)p; p += 576*64*2;
    unsigned short* WtP  = (unsigned short*)p; p += 1728*64*2;
    unsigned short* X = (unsigned short*)p; p += (size_t)SP*32*2;
    unsigned short* P = (unsigned short*)p; p += (size_t)SP*64*2;
    unsigned short* Q = (unsigned short*)p; p += (size_t)SP*64*2;
    unsigned short* R = (unsigned short*)p; p += (size_t)SP*64*2;

    float* down = (float*)d_out;                 // [64][OSP]
    float* resf = down + (size_t)CO*OSP;         // [64][SP]

    hipMemsetAsync(statsN, 0, (4*NSC*128 + 4*128 + NSC)*4 + 4, stream);
    k_detect<<<256, 256, 0, stream>>>((const unsigned char*)mraw, flag);
    k_mask<<<SP/256, 256, 0, stream>>>(mraw, flag, m, nactN);
    k_outmask<<<OSP/256, 256, 0, stream>>>(m, omask);
    k_prep_x<<<SP/64, 256, 0, stream>>>(x, m, X);

    k_wprep<<<(64*288+255)/256, 256, 0, stream>>>(W_A1, WtA1, 32, 9);
    k_wprep<<<(64*576+255)/256, 256, 0, stream>>>(W_A2, WtA2, 64, 9);
    k_wprep<<<(64*288+255)/256, 256, 0, stream>>>(W_B1, WtB1, 32, 9);
    k_wprep<<<(64*576+255)/256, 256, 0, stream>>>(W_B2, WtB2, 64, 9);
    k_wprep<<<(64*1728+255)/256, 256, 0, stream>>>(W_pool, WtP, 64, 27);

    float* SA1 = statsN + 0*NSC*128;
    float* SA2 = statsN + 1*NSC*128;
    float* SB1 = statsN + 2*NSC*128;
    float* SB2 = statsN + 3*NSC*128;

    // stage 1: A1 and B1 (both read X)
    mconv5<0,32,false><<<3200, 256, 0, stream>>>(X, WtA1, nullptr, nullptr, m, P, nullptr, SA1);
    mconv5<1,32,false><<<3200, 256, 0, stream>>>(X, WtB1, nullptr, nullptr, m, Q, nullptr, SB1);
    k_finalize2<<<2, 64, 0, stream>>>(SA1, g_A1, b_A1, scsh + 0,
                                      SB1, g_B1, b_B1, scsh + 256, nactN);
    // stage 2: A2 on BN_A1(P), B2 on BN_B1(Q)
    mconv5<1,64,true><<<3200, 256, 0, stream>>>(P, WtA2, scsh + 0,   m, m, R, nullptr, SA2);
    mconv5<0,64,true><<<3200, 256, 0, stream>>>(Q, WtB2, scsh + 256, m, m, P, nullptr, SB2);
    k_finalize2<<<2, 64, 0, stream>>>(SA2, g_A2, b_A2, scsh + 128,
                                      SB2, g_B2, b_B2, scsh + 384, nactN);
    // res_B combine -> Q (bf16 for pool) + resf (f32 output)
    k_resB<<<SP/64, 256, 0, stream>>>(R, P, scsh + 128, scsh + 384, m, Q, resf);
    // pool
    mconv5<2,64,false><<<1600, 256, 0, stream>>>(Q, WtP, nullptr, nullptr, omask, nullptr, down, nullptr);
}